// Round 18
// baseline (1200.988 us; speedup 1.0000x reference)
//
#include <hip/hip_runtime.h>
#include <hip/hip_bf16.h>

#define BT 16384
#define NB 8192
#define DD 256
#define MARGIN 2e-4f

typedef short bf16x8 __attribute__((ext_vector_type(8)));
typedef unsigned short u16x8 __attribute__((ext_vector_type(8)));
typedef float f32x4 __attribute__((ext_vector_type(4)));
typedef __attribute__((address_space(1))) unsigned int gu32;
typedef __attribute__((address_space(3))) unsigned int lu32;

// ---- fast-path ws layout (bytes) ----
#define W2_WTILE 0
#define W2_PM1   (8*1024*1024)
#define W2_PM2   (W2_PM1 + 2*BT*4)
#define W2_PI1   (W2_PM2 + 2*BT*4)
#define W2_IDX   (W2_PI1 + 2*BT*4)
#define W2_CNT   (W2_IDX + BT*4)
#define W2_LIST  (W2_CNT + 256)
#define W2_NEED  ((size_t)(W2_LIST + BT*4))

// ---- fallback ws layout (round-4, validated) ----
#define WS_INV  0
#define WS_WSQ  (BT*4)
#define WS_IDX  (WS_WSQ + NB*4)
#define WS_CNT  (WS_IDX + BT*4)
#define WS_LIST (WS_CNT + 64)

__device__ __forceinline__ unsigned int f2bf(float f) {
    unsigned int u = __float_as_uint(f);
    return (u + 0x7FFFu + ((u >> 16) & 1u)) >> 16;
}

__device__ __forceinline__ void split8(const float4 a, const float4 b, u16x8 &hv, u16x8 &lv) {
    float xs[8] = {a.x, a.y, a.z, a.w, b.x, b.y, b.z, b.w};
    #pragma unroll
    for (int i = 0; i < 8; ++i) {
        unsigned int h = f2bf(xs[i]);
        hv[i] = (unsigned short)h;
        lv[i] = (unsigned short)f2bf(xs[i] - __uint_as_float(h << 16));
    }
}

// ================= FAST PATH =================

// Fused prep: blocks 0..511 = zsplit (normalize+split z), 512..639 = wsplit.
// zsplit layout (16x16x32 fragment-major): for 16-row tile tau, kstep ks,
// lane l: row = tau*16+(l&15), k = ks*32+(l>>4)*8 .. +8.
// zt[(tau*8+ks)*64 + l] = hi ; +524288 = lo.
__global__ void prep_kernel(const float* __restrict__ z,
                            const float* __restrict__ w,
                            u16x8* __restrict__ zt,
                            unsigned short* __restrict__ wtile) {
    const int t = threadIdx.x;
    if (blockIdx.x >= 512) {
        // ---- wsplit: [ch][p 2][slot 32][code 64][8] bf16 ----
        const int ch = blockIdx.x - 512;
        const int c  = t >> 2;
        const int q  = t & 3;
        const float* wr = w + (size_t)(ch * 64 + c) * DD + q * 64;
        unsigned short* base = wtile + (size_t)ch * 32768;
        #pragma unroll
        for (int g = 0; g < 8; ++g) {
            float4 v0 = reinterpret_cast<const float4*>(wr)[2 * g];
            float4 v1 = reinterpret_cast<const float4*>(wr)[2 * g + 1];
            u16x8 hv, lv;
            split8(v0, v1, hv, lv);
            const int slot = q * 8 + g;
            *reinterpret_cast<u16x8*>(base + ((size_t)slot * 64 + c) * 8) = hv;
            *reinterpret_cast<u16x8*>(base + ((size_t)(32 + slot) * 64 + c) * 8) = lv;
        }
        return;
    }
    __shared__ float inv_s[32];
    const int rt = blockIdx.x;           // 32 rows per block
    {
        const int rl = t >> 3, sub = t & 7;
        const float4* zr = reinterpret_cast<const float4*>(
            z + (size_t)(rt * 32 + rl) * DD + sub * 32);
        double s = 0.0;
        #pragma unroll
        for (int i = 0; i < 8; ++i) {
            float4 v = zr[i];
            s += (double)v.x*v.x + (double)v.y*v.y + (double)v.z*v.z + (double)v.w*v.w;
        }
        s += __shfl_xor(s, 1, 64);
        s += __shfl_xor(s, 2, 64);
        s += __shfl_xor(s, 4, 64);
        if (sub == 0) {
            double n = sqrt(s);
            if (n < 1e-12) n = 1e-12;
            inv_s[rl] = (float)(1.0 / n);
        }
    }
    __syncthreads();
    const int sg = t >> 6, l = t & 63;
    const int tau  = rt * 2 + (sg >> 1);
    const int rowl = (sg >> 1) * 16 + (l & 15);
    const int row  = rt * 32 + rowl;
    const float inv = inv_s[rowl];
    #pragma unroll
    for (int ksi = 0; ksi < 4; ++ksi) {
        const int ks = (sg & 1) * 4 + ksi;
        const int k0 = ks * 32 + (l >> 4) * 8;
        float4 a = *reinterpret_cast<const float4*>(z + (size_t)row * DD + k0);
        float4 b = *reinterpret_cast<const float4*>(z + (size_t)row * DD + k0 + 4);
        a.x *= inv; a.y *= inv; a.z *= inv; a.w *= inv;
        b.x *= inv; b.y *= inv; b.z *= inv; b.w *= inv;
        u16x8 hv, lv;
        split8(a, b, hv, lv);
        const size_t o = ((size_t)tau * 8 + ks) * 64 + l;
        zt[o] = hv;
        zt[524288 + o] = lv;
    }
}

// Fused MFMA argmin, 16x16x32 (round-15 validated: 257us, no spill).
// 256 blocks x 512 thr. Per wave: 16 rows (A = 64 regs, AGPR-resident),
// all 64 chunk-codes as 4 col-tiles (4 independent acc chains).
__launch_bounds__(512, 1)
__global__ void argmin2(const u16x8* __restrict__ zt,
                        const unsigned short* __restrict__ wtile,
                        float* __restrict__ pm1,
                        float* __restrict__ pm2,
                        int* __restrict__ pi1) {
    __shared__ __align__(16) unsigned short Bbuf[2][2][32][64][8]; // 128 KB
    const int t = threadIdx.x, lane = t & 63, wv = t >> 6;
    const int b = blockIdx.x;
    const int rb   = b >> 1;
    const int half = b & 1;              // XCD parity -> one 4MB half per XCD L2
    const int r0   = rb * 128;
    const int tau  = rb * 8 + wv;        // this wave's 16-row tile
    const int lc = lane & 15;            // code-in-tile (B col / C col)
    const int lk = lane >> 4;            // k-subgroup (and C row-group)

    // ---- A-frags into registers: 8 ksteps x (hi,lo) = 64 regs ----
    const bf16x8* zf = reinterpret_cast<const bf16x8*>(zt);
    bf16x8 ah[8], al[8];
    #pragma unroll
    for (int ks = 0; ks < 8; ++ks) {
        const size_t o = ((size_t)tau * 8 + ks) * 64 + lane;
        ah[ks] = zf[o];
        al[ks] = zf[524288 + o];
    }

    float m1[4], m2[4]; int i1[4];
    #pragma unroll
    for (int j = 0; j < 4; ++j) { m1[j] = INFINITY; m2[j] = INFINITY; i1[j] = 0; }

    const unsigned short* wsrc = wtile + (size_t)half * 2097152 + (size_t)t * 8;
    unsigned short* dst0 = &Bbuf[0][0][0][0][0] + (size_t)t * 8;
    unsigned short* dst1 = &Bbuf[1][0][0][0][0] + (size_t)t * 8;

    {   // prologue: chunk 0 -> buf 0
        #pragma unroll
        for (int i = 0; i < 8; ++i)
            __builtin_amdgcn_global_load_lds((gu32*)(wsrc + i * 4096),
                                             (lu32*)(dst0 + i * 4096), 16, 0, 0);
    }

    int cur = 0;
    for (int ch = 0; ch < 64; ++ch) {
        if (ch < 63) {
            const unsigned short* src = wsrc + (size_t)(ch + 1) * 32768;
            unsigned short* dst = cur ? dst0 : dst1;
            #pragma unroll
            for (int i = 0; i < 8; ++i)
                __builtin_amdgcn_global_load_lds((gu32*)(src + i * 4096),
                                                 (lu32*)(dst + i * 4096), 16, 0, 0);
            asm volatile("s_waitcnt vmcnt(8)" ::: "memory");
        } else {
            asm volatile("s_waitcnt vmcnt(0)" ::: "memory");
        }
        __builtin_amdgcn_s_barrier();
        __builtin_amdgcn_sched_barrier(0);

        f32x4 a0 = {0.f,0.f,0.f,0.f}, a1 = a0, a2 = a0, a3 = a0;

        #pragma unroll
        for (int ks = 0; ks < 8; ++ks) {
            const int slot = ks * 4 + lk;
            const bf16x8* Bh = reinterpret_cast<const bf16x8*>(&Bbuf[cur][0][slot][0][0]);
            const bf16x8* Bl = reinterpret_cast<const bf16x8*>(&Bbuf[cur][1][slot][0][0]);
            bf16x8 bh, bl;
            bh = Bh[lc];      bl = Bl[lc];
            a0 = __builtin_amdgcn_mfma_f32_16x16x32_bf16(ah[ks], bh, a0, 0, 0, 0);
            a0 = __builtin_amdgcn_mfma_f32_16x16x32_bf16(ah[ks], bl, a0, 0, 0, 0);
            a0 = __builtin_amdgcn_mfma_f32_16x16x32_bf16(al[ks], bh, a0, 0, 0, 0);
            bh = Bh[16 + lc]; bl = Bl[16 + lc];
            a1 = __builtin_amdgcn_mfma_f32_16x16x32_bf16(ah[ks], bh, a1, 0, 0, 0);
            a1 = __builtin_amdgcn_mfma_f32_16x16x32_bf16(ah[ks], bl, a1, 0, 0, 0);
            a1 = __builtin_amdgcn_mfma_f32_16x16x32_bf16(al[ks], bh, a1, 0, 0, 0);
            bh = Bh[32 + lc]; bl = Bl[32 + lc];
            a2 = __builtin_amdgcn_mfma_f32_16x16x32_bf16(ah[ks], bh, a2, 0, 0, 0);
            a2 = __builtin_amdgcn_mfma_f32_16x16x32_bf16(ah[ks], bl, a2, 0, 0, 0);
            a2 = __builtin_amdgcn_mfma_f32_16x16x32_bf16(al[ks], bh, a2, 0, 0, 0);
            bh = Bh[48 + lc]; bl = Bl[48 + lc];
            a3 = __builtin_amdgcn_mfma_f32_16x16x32_bf16(ah[ks], bh, a3, 0, 0, 0);
            a3 = __builtin_amdgcn_mfma_f32_16x16x32_bf16(ah[ks], bl, a3, 0, 0, 0);
            a3 = __builtin_amdgcn_mfma_f32_16x16x32_bf16(al[ks], bh, a3, 0, 0, 0);
        }

        const int nb = half * 4096 + ch * 64 + lc;
        #pragma unroll
        for (int j = 0; j < 4; ++j) {
            float v;
            v = -2.0f * a0[j];
            if (v < m1[j]) { m2[j] = m1[j]; m1[j] = v; i1[j] = nb; }
            else if (v < m2[j]) m2[j] = v;
            v = -2.0f * a1[j];
            if (v < m1[j]) { m2[j] = m1[j]; m1[j] = v; i1[j] = nb + 16; }
            else if (v < m2[j]) m2[j] = v;
            v = -2.0f * a2[j];
            if (v < m1[j]) { m2[j] = m1[j]; m1[j] = v; i1[j] = nb + 32; }
            else if (v < m2[j]) m2[j] = v;
            v = -2.0f * a3[j];
            if (v < m1[j]) { m2[j] = m1[j]; m1[j] = v; i1[j] = nb + 48; }
            else if (v < m2[j]) m2[j] = v;
        }

        __builtin_amdgcn_sched_barrier(0);
        __builtin_amdgcn_s_barrier();
        cur ^= 1;
    }

    // reduce across the 16 code-lanes of each row-group (ties -> smaller idx)
    #pragma unroll
    for (int off = 1; off < 16; off <<= 1) {
        #pragma unroll
        for (int j = 0; j < 4; ++j) {
            float om1 = __shfl_xor(m1[j], off, 64);
            float om2 = __shfl_xor(m2[j], off, 64);
            int   oi  = __shfl_xor(i1[j], off, 64);
            if (om1 < m1[j] || (om1 == m1[j] && oi < i1[j])) {
                m2[j] = fminf(m1[j], om2); m1[j] = om1; i1[j] = oi;
            } else {
                m2[j] = fminf(om1, m2[j]);
            }
        }
    }
    if (lc == 0) {
        #pragma unroll
        for (int j = 0; j < 4; ++j) {
            const int row = r0 + wv * 16 + lk * 4 + j;   // C row = (lane>>4)*4+j
            pm1[half * BT + row] = m1[j];
            pm2[half * BT + row] = m2[j];
            pi1[half * BT + row] = i1[j];
        }
    }
}

// merge the two code-halves per row; flag near-ties for refine
__global__ void merge_kernel(const float* __restrict__ pm1,
                             const float* __restrict__ pm2,
                             const int* __restrict__ pi1,
                             int* __restrict__ idx_out,
                             int* __restrict__ counter,
                             int* __restrict__ list) {
    const int r = blockIdx.x * 256 + threadIdx.x;
    float a1 = pm1[r], a2 = pm2[r]; int ai = pi1[r];
    float b1 = pm1[BT + r], b2 = pm2[BT + r]; int bi = pi1[BT + r];
    float f1, f2; int fi;
    if (b1 < a1 || (b1 == a1 && bi < ai)) { f1 = b1; fi = bi; f2 = fminf(a1, b2); }
    else                                  { f1 = a1; fi = ai; f2 = fminf(b1, a2); }
    idx_out[r] = fi;
    if (f2 - f1 < MARGIN) {
        int p = atomicAdd(counter, 1);
        list[p] = r;
    }
}

// ================= SHARED (refine / gather) =================

// refine v3: COALESCED wave-cooperative f32 scan (round-17's phase A kept the
// old stride-1KB per-lane pattern -> latency-bound 264us). Each wave handles
// one code per iteration: lane l reads w[n*256+4l..+4] (contiguous 1KB/wave),
// partial d = |w|^2 - 2 w.zn reduced via shfl. dist[] in LDS; exact f64 only
// on candidates within min+1e-3 (f32 scan error <=~1e-4).
__global__ void refine_kernel(const float* __restrict__ z,
                              const float* __restrict__ w,
                              const int* __restrict__ counter,
                              const int* __restrict__ list,
                              int* __restrict__ idx_out) {
    __shared__ double zn_s[256];
    __shared__ float  znf[256];
    __shared__ float  dist[NB];      // 32 KB
    __shared__ double rv[256];
    __shared__ int    ri[256];
    __shared__ float  fm[256];
    const int t = threadIdx.x;
    const int lane = t & 63;
    const int wv = t >> 6;           // 4 waves
    const int cnt = *counter;
    for (int item = blockIdx.x; item < cnt; item += gridDim.x) {
        const int row = list[item];
        double zv = (double)z[(size_t)row * DD + t];
        __syncthreads();
        rv[t] = zv * zv;
        __syncthreads();
        for (int s = 128; s; s >>= 1) { if (t < s) rv[t] += rv[t + s]; __syncthreads(); }
        double norm = sqrt(rv[0]);
        if (norm < 1e-12) norm = 1e-12;
        __syncthreads();
        zn_s[t] = zv / norm;
        znf[t] = (float)(zv / norm);
        __syncthreads();

        // lane-resident zn fragment (constant across codes)
        const float4 zn4 = *reinterpret_cast<const float4*>(&znf[lane * 4]);

        // ---- phase A: coalesced f32 scan, one code per wave-iteration ----
        for (int n = wv; n < NB; n += 4) {
            float4 v = *reinterpret_cast<const float4*>(w + (size_t)n * DD + lane * 4);
            float d = (v.x * v.x + v.y * v.y + v.z * v.z + v.w * v.w)
                    - 2.f * (v.x * zn4.x + v.y * zn4.y + v.z * zn4.z + v.w * zn4.w);
            #pragma unroll
            for (int off = 32; off; off >>= 1) d += __shfl_down(d, off, 64);
            if (lane == 0) dist[n] = d;
        }
        __syncthreads();

        // ---- block min of dist ----
        float best = INFINITY;
        #pragma unroll
        for (int j = 0; j < NB / 256; ++j) best = fminf(best, dist[t + 256 * j]);
        fm[t] = best;
        __syncthreads();
        for (int s = 128; s; s >>= 1) { if (t < s) fm[t] = fminf(fm[t], fm[t + s]); __syncthreads(); }
        const float thresh = fm[0] + 1e-3f;

        // ---- phase B: exact f64 on candidates only ----
        double bv = INFINITY; int bi = 0x7fffffff;
        for (int j = 0; j < NB / 256; ++j) {
            const int n = t + 256 * j;
            if (dist[n] <= thresh) {
                const float* wr = w + (size_t)n * DD;
                double dot = 0.0, wsqd = 0.0;
                for (int k = 0; k < DD; ++k) {
                    double wvv = (double)wr[k];
                    dot  += zn_s[k] * wvv;
                    wsqd += wvv * wvv;
                }
                double d2 = wsqd - 2.0 * dot;
                if (d2 < bv || (d2 == bv && n < bi)) { bv = d2; bi = n; }
            }
        }
        __syncthreads();
        rv[t] = bv; ri[t] = bi;
        __syncthreads();
        for (int s = 128; s; s >>= 1) {
            if (t < s) {
                if (rv[t + s] < rv[t] || (rv[t + s] == rv[t] && ri[t + s] < ri[t])) {
                    rv[t] = rv[t + s]; ri[t] = ri[t + s];
                }
            }
            __syncthreads();
        }
        if (t == 0) idx_out[row] = ri[0];
        __syncthreads();
    }
}

__global__ void gather_kernel(const float* __restrict__ w,
                              const int* __restrict__ idx,
                              float* __restrict__ out) {
    const int t = threadIdx.x;
    const int blk = blockIdx.x;
    const int row = blk * 8 + (t >> 5);
    const int lane = t & 31;
    int n = idx[row];
    if ((unsigned)n >= (unsigned)NB) n = 0;
    const float4* src = reinterpret_cast<const float4*>(w + (size_t)n * DD + lane * 8);
    float4 v0 = src[0], v1 = src[1];
    float4* dst = reinterpret_cast<float4*>(out + (size_t)row * DD + lane * 8);
    dst[0] = v0;
    dst[1] = v1;
    if (t < 8) {
        int r2 = blk * 8 + t;
        out[(size_t)BT * DD + r2] = (float)idx[r2];
    }
}

// ================= FALLBACK (round-4, validated) =================

__global__ void rownorm_kernel(const float* __restrict__ x, int rows,
                               float* __restrict__ out, int mode) {
    int row  = blockIdx.x * 4 + (threadIdx.x >> 6);
    int lane = threadIdx.x & 63;
    if (row >= rows) return;
    const float4 v = *reinterpret_cast<const float4*>(x + (size_t)row * DD + lane * 4);
    double s = (double)v.x * v.x + (double)v.y * v.y + (double)v.z * v.z + (double)v.w * v.w;
    #pragma unroll
    for (int off = 32; off; off >>= 1) s += __shfl_down(s, off, 64);
    if (lane == 0) {
        if (mode == 0) {
            double n = sqrt(s);
            if (n < 1e-12) n = 1e-12;
            out[row] = (float)(1.0 / n);
        } else {
            out[row] = (float)s;
        }
    }
}

__launch_bounds__(256, 1)
__global__ void argmin_mfma(const float* __restrict__ z,
                            const float* __restrict__ w,
                            const float* __restrict__ invn,
                            const float* __restrict__ wsq,
                            int* __restrict__ idx_out,
                            int* __restrict__ counter,
                            int* __restrict__ list) {
    __shared__ unsigned short Ahi[64][256];
    __shared__ unsigned short Alo[64][256];
    __shared__ unsigned short Bhi[64][256];
    __shared__ unsigned short Blo[64][256];
    __shared__ float wsq_s[64];
    __shared__ float red_m1[2][64];
    __shared__ float red_m2[2][64];
    __shared__ int   red_i1[2][64];

    typedef float f32x16 __attribute__((ext_vector_type(16)));
    const int t    = threadIdx.x;
    const int lane = t & 63;
    const int wvv  = t >> 6;
    const int wy = wvv >> 1, wx = wvv & 1;
    const int l5 = lane >> 5, lq = lane & 31;
    const int r0 = blockIdx.x * 64;

    {
        const int ar = t >> 2;
        const int sbase = (t & 3) * 8;
        const float* zr = z + (size_t)(r0 + ar) * DD + (t & 3) * 64;
        #pragma unroll
        for (int g = 0; g < 8; ++g) {
            float4 v0 = reinterpret_cast<const float4*>(zr)[2 * g];
            float4 v1 = reinterpret_cast<const float4*>(zr)[2 * g + 1];
            u16x8 hv, lv;
            split8(v0, v1, hv, lv);
            int slot = (sbase + g) ^ (ar & 7);
            *reinterpret_cast<u16x8*>(&Ahi[ar][slot * 8]) = hv;
            *reinterpret_cast<u16x8*>(&Alo[ar][slot * 8]) = lv;
        }
    }

    float twoinv[16];
    #pragma unroll
    for (int r = 0; r < 16; ++r)
        twoinv[r] = 2.0f * invn[r0 + wy * 32 + (r & 3) + 8 * (r >> 2) + 4 * l5];

    float m1[16], m2[16]; int i1[16];
    #pragma unroll
    for (int r = 0; r < 16; ++r) { m1[r] = INFINITY; m2[r] = INFINITY; i1[r] = 0; }

    const int cc = t >> 2;
    const int sbase = (t & 3) * 8;
    float4 pre[16];
    {
        const float* wb = w + (size_t)cc * DD + (t & 3) * 64;
        #pragma unroll
        for (int q = 0; q < 16; ++q) pre[q] = reinterpret_cast<const float4*>(wb)[q];
    }
    float wsq_pre = (t < 64) ? wsq[t] : 0.f;

    const int am = wy * 32 + lq;
    const int bn = wx * 32 + lq;
    const int sxor = lq & 7;

    for (int ch = 0; ch < 128; ++ch) {
        __syncthreads();
        #pragma unroll
        for (int g = 0; g < 8; ++g) {
            u16x8 hv, lv;
            split8(pre[2 * g], pre[2 * g + 1], hv, lv);
            int slot = (sbase + g) ^ (cc & 7);
            *reinterpret_cast<u16x8*>(&Bhi[cc][slot * 8]) = hv;
            *reinterpret_cast<u16x8*>(&Blo[cc][slot * 8]) = lv;
        }
        if (t < 64) wsq_s[t] = wsq_pre;
        __syncthreads();

        if (ch < 127) {
            const float* wb = w + (size_t)((ch + 1) * 64 + cc) * DD + (t & 3) * 64;
            #pragma unroll
            for (int q = 0; q < 16; ++q) pre[q] = reinterpret_cast<const float4*>(wb)[q];
            if (t < 64) wsq_pre = wsq[(ch + 1) * 64 + t];
        }

        f32x16 acc0, acc1;
        #pragma unroll
        for (int r = 0; r < 16; ++r) { acc0[r] = 0.f; acc1[r] = 0.f; }

        #pragma unroll
        for (int s = 0; s < 16; ++s) {
            const int sl = (2 * s + l5) ^ sxor;
            bf16x8 ah = *reinterpret_cast<const bf16x8*>(&Ahi[am][sl * 8]);
            bf16x8 al = *reinterpret_cast<const bf16x8*>(&Alo[am][sl * 8]);
            bf16x8 bh = *reinterpret_cast<const bf16x8*>(&Bhi[bn][sl * 8]);
            bf16x8 bl = *reinterpret_cast<const bf16x8*>(&Blo[bn][sl * 8]);
            acc0 = __builtin_amdgcn_mfma_f32_32x32x16_bf16(ah, bh, acc0, 0, 0, 0);
            acc1 = __builtin_amdgcn_mfma_f32_32x32x16_bf16(ah, bl, acc1, 0, 0, 0);
            acc0 = __builtin_amdgcn_mfma_f32_32x32x16_bf16(al, bh, acc0, 0, 0, 0);
        }

        const float wq = wsq_s[bn];
        const int nidx = ch * 64 + bn;
        #pragma unroll
        for (int r = 0; r < 16; ++r) {
            float v = wq - twoinv[r] * (acc0[r] + acc1[r]);
            if (v < m1[r]) { m2[r] = m1[r]; m1[r] = v; i1[r] = nidx; }
            else if (v < m2[r]) m2[r] = v;
        }
    }

    #pragma unroll
    for (int off = 1; off < 32; off <<= 1) {
        #pragma unroll
        for (int r = 0; r < 16; ++r) {
            float om1 = __shfl_xor(m1[r], off, 64);
            float om2 = __shfl_xor(m2[r], off, 64);
            int   oi  = __shfl_xor(i1[r], off, 64);
            if (om1 < m1[r] || (om1 == m1[r] && oi < i1[r])) {
                m2[r] = fminf(m1[r], om2); m1[r] = om1; i1[r] = oi;
            } else {
                m2[r] = fminf(om1, m2[r]);
            }
        }
    }
    if (lq == 0) {
        #pragma unroll
        for (int r = 0; r < 16; ++r) {
            int ml = wy * 32 + (r & 3) + 8 * (r >> 2) + 4 * l5;
            red_m1[wx][ml] = m1[r];
            red_m2[wx][ml] = m2[r];
            red_i1[wx][ml] = i1[r];
        }
    }
    __syncthreads();
    if (t < 64) {
        float a1 = red_m1[0][t], a2 = red_m2[0][t]; int ai = red_i1[0][t];
        float b1 = red_m1[1][t], b2 = red_m2[1][t]; int bi = red_i1[1][t];
        float f1, f2; int fi;
        if (b1 < a1 || (b1 == a1 && bi < ai)) { f1 = b1; fi = bi; f2 = fminf(a1, b2); }
        else                                  { f1 = a1; fi = ai; f2 = fminf(b1, a2); }
        idx_out[r0 + t] = fi;
        if (f2 - f1 < MARGIN) {
            int p = atomicAdd(counter, 1);
            list[p] = r0 + t;
        }
    }
}

extern "C" void kernel_launch(void* const* d_in, const int* in_sizes, int n_in,
                              void* d_out, int out_size, void* d_ws, size_t ws_size,
                              hipStream_t stream) {
    const float* z = (const float*)d_in[0];
    const float* w = (const float*)d_in[1];
    float* out = (float*)d_out;
    char* ws = (char*)d_ws;

    if (ws_size >= W2_NEED) {
        unsigned short* wtile = (unsigned short*)(ws + W2_WTILE);
        float* pm1 = (float*)(ws + W2_PM1);
        float* pm2 = (float*)(ws + W2_PM2);
        int*   pi1 = (int*)(ws + W2_PI1);
        int*   idx = (int*)(ws + W2_IDX);
        int*   cnt = (int*)(ws + W2_CNT);
        int*   list = (int*)(ws + W2_LIST);
        u16x8* zt = (u16x8*)d_out;     // z_q region doubles as zt scratch

        hipMemsetAsync(cnt, 0, 4, stream);
        prep_kernel<<<640, 256, 0, stream>>>(z, w, zt, wtile);
        argmin2<<<256, 512, 0, stream>>>(zt, wtile, pm1, pm2, pi1);
        merge_kernel<<<64, 256, 0, stream>>>(pm1, pm2, pi1, idx, cnt, list);
        refine_kernel<<<256, 256, 0, stream>>>(z, w, cnt, list, idx);
        gather_kernel<<<BT / 8, 256, 0, stream>>>(w, idx, out);
    } else {
        float* inv  = (float*)(ws + WS_INV);
        float* wsq  = (float*)(ws + WS_WSQ);
        int*   idx  = (int*)(ws + WS_IDX);
        int*   cnt  = (int*)(ws + WS_CNT);
        int*   list = (int*)(ws + WS_LIST);

        hipMemsetAsync(cnt, 0, 4, stream);
        rownorm_kernel<<<BT / 4, 256, 0, stream>>>(z, BT, inv, 0);
        rownorm_kernel<<<NB / 4, 256, 0, stream>>>(w, NB, wsq, 1);
        argmin_mfma<<<BT / 64, 256, 0, stream>>>(z, w, inv, wsq, idx, cnt, list);
        refine_kernel<<<64, 256, 0, stream>>>(z, w, cnt, list, idx);
        gather_kernel<<<BT / 8, 256, 0, stream>>>(w, idx, out);
    }
}

// Round 19
// 602.116 us; speedup vs baseline: 1.9946x; 1.9946x over previous
//
#include <hip/hip_runtime.h>
#include <hip/hip_bf16.h>

#define BT 16384
#define NB 8192
#define DD 256
#define MARGIN 2e-4f

typedef short bf16x8 __attribute__((ext_vector_type(8)));
typedef unsigned short u16x8 __attribute__((ext_vector_type(8)));
typedef float f32x4 __attribute__((ext_vector_type(4)));
typedef __attribute__((address_space(1))) unsigned int gu32;
typedef __attribute__((address_space(3))) unsigned int lu32;

// ---- fast-path ws layout (bytes) ----
#define W2_WTILE 0
#define W2_PM1   (8*1024*1024)
#define W2_PM2   (W2_PM1 + 2*BT*4)
#define W2_PI1   (W2_PM2 + 2*BT*4)
#define W2_IDX   (W2_PI1 + 2*BT*4)
#define W2_CNT   (W2_IDX + BT*4)
#define W2_LIST  (W2_CNT + 256)
#define W2_NEED  ((size_t)(W2_LIST + BT*4))

// ---- fallback ws layout (round-4, validated) ----
#define WS_INV  0
#define WS_WSQ  (BT*4)
#define WS_IDX  (WS_WSQ + NB*4)
#define WS_CNT  (WS_IDX + BT*4)
#define WS_LIST (WS_CNT + 64)

__device__ __forceinline__ unsigned int f2bf(float f) {
    unsigned int u = __float_as_uint(f);
    return (u + 0x7FFFu + ((u >> 16) & 1u)) >> 16;
}

__device__ __forceinline__ void split8(const float4 a, const float4 b, u16x8 &hv, u16x8 &lv) {
    float xs[8] = {a.x, a.y, a.z, a.w, b.x, b.y, b.z, b.w};
    #pragma unroll
    for (int i = 0; i < 8; ++i) {
        unsigned int h = f2bf(xs[i]);
        hv[i] = (unsigned short)h;
        lv[i] = (unsigned short)f2bf(xs[i] - __uint_as_float(h << 16));
    }
}

// ================= FAST PATH =================

// Fused prep: blocks 0..511 = zsplit (normalize+split z), 512..639 = wsplit.
// zsplit layout (16x16x32 fragment-major): for 16-row tile tau, kstep ks,
// lane l: row = tau*16+(l&15), k = ks*32+(l>>4)*8 .. +8.
// zt[(tau*8+ks)*64 + l] = hi ; +524288 = lo.
__global__ void prep_kernel(const float* __restrict__ z,
                            const float* __restrict__ w,
                            u16x8* __restrict__ zt,
                            unsigned short* __restrict__ wtile) {
    const int t = threadIdx.x;
    if (blockIdx.x >= 512) {
        // ---- wsplit: [ch][p 2][slot 32][code 64][8] bf16 ----
        const int ch = blockIdx.x - 512;
        const int c  = t >> 2;
        const int q  = t & 3;
        const float* wr = w + (size_t)(ch * 64 + c) * DD + q * 64;
        unsigned short* base = wtile + (size_t)ch * 32768;
        #pragma unroll
        for (int g = 0; g < 8; ++g) {
            float4 v0 = reinterpret_cast<const float4*>(wr)[2 * g];
            float4 v1 = reinterpret_cast<const float4*>(wr)[2 * g + 1];
            u16x8 hv, lv;
            split8(v0, v1, hv, lv);
            const int slot = q * 8 + g;
            *reinterpret_cast<u16x8*>(base + ((size_t)slot * 64 + c) * 8) = hv;
            *reinterpret_cast<u16x8*>(base + ((size_t)(32 + slot) * 64 + c) * 8) = lv;
        }
        return;
    }
    __shared__ float inv_s[32];
    const int rt = blockIdx.x;           // 32 rows per block
    {
        const int rl = t >> 3, sub = t & 7;
        const float4* zr = reinterpret_cast<const float4*>(
            z + (size_t)(rt * 32 + rl) * DD + sub * 32);
        double s = 0.0;
        #pragma unroll
        for (int i = 0; i < 8; ++i) {
            float4 v = zr[i];
            s += (double)v.x*v.x + (double)v.y*v.y + (double)v.z*v.z + (double)v.w*v.w;
        }
        s += __shfl_xor(s, 1, 64);
        s += __shfl_xor(s, 2, 64);
        s += __shfl_xor(s, 4, 64);
        if (sub == 0) {
            double n = sqrt(s);
            if (n < 1e-12) n = 1e-12;
            inv_s[rl] = (float)(1.0 / n);
        }
    }
    __syncthreads();
    const int sg = t >> 6, l = t & 63;
    const int tau  = rt * 2 + (sg >> 1);
    const int rowl = (sg >> 1) * 16 + (l & 15);
    const int row  = rt * 32 + rowl;
    const float inv = inv_s[rowl];
    #pragma unroll
    for (int ksi = 0; ksi < 4; ++ksi) {
        const int ks = (sg & 1) * 4 + ksi;
        const int k0 = ks * 32 + (l >> 4) * 8;
        float4 a = *reinterpret_cast<const float4*>(z + (size_t)row * DD + k0);
        float4 b = *reinterpret_cast<const float4*>(z + (size_t)row * DD + k0 + 4);
        a.x *= inv; a.y *= inv; a.z *= inv; a.w *= inv;
        b.x *= inv; b.y *= inv; b.z *= inv; b.w *= inv;
        u16x8 hv, lv;
        split8(a, b, hv, lv);
        const size_t o = ((size_t)tau * 8 + ks) * 64 + l;
        zt[o] = hv;
        zt[524288 + o] = lv;
    }
}

// Fused MFMA argmin, 16x16x32 (round-15 validated: 257us, no spill).
// 256 blocks x 512 thr. Per wave: 16 rows (A = 64 regs, AGPR-resident),
// all 64 chunk-codes as 4 col-tiles (4 independent acc chains).
__launch_bounds__(512, 1)
__global__ void argmin2(const u16x8* __restrict__ zt,
                        const unsigned short* __restrict__ wtile,
                        float* __restrict__ pm1,
                        float* __restrict__ pm2,
                        int* __restrict__ pi1) {
    __shared__ __align__(16) unsigned short Bbuf[2][2][32][64][8]; // 128 KB
    const int t = threadIdx.x, lane = t & 63, wv = t >> 6;
    const int b = blockIdx.x;
    const int rb   = b >> 1;
    const int half = b & 1;              // XCD parity -> one 4MB half per XCD L2
    const int r0   = rb * 128;
    const int tau  = rb * 8 + wv;        // this wave's 16-row tile
    const int lc = lane & 15;            // code-in-tile (B col / C col)
    const int lk = lane >> 4;            // k-subgroup (and C row-group)

    // ---- A-frags into registers: 8 ksteps x (hi,lo) = 64 regs ----
    const bf16x8* zf = reinterpret_cast<const bf16x8*>(zt);
    bf16x8 ah[8], al[8];
    #pragma unroll
    for (int ks = 0; ks < 8; ++ks) {
        const size_t o = ((size_t)tau * 8 + ks) * 64 + lane;
        ah[ks] = zf[o];
        al[ks] = zf[524288 + o];
    }

    float m1[4], m2[4]; int i1[4];
    #pragma unroll
    for (int j = 0; j < 4; ++j) { m1[j] = INFINITY; m2[j] = INFINITY; i1[j] = 0; }

    const unsigned short* wsrc = wtile + (size_t)half * 2097152 + (size_t)t * 8;
    unsigned short* dst0 = &Bbuf[0][0][0][0][0] + (size_t)t * 8;
    unsigned short* dst1 = &Bbuf[1][0][0][0][0] + (size_t)t * 8;

    {   // prologue: chunk 0 -> buf 0
        #pragma unroll
        for (int i = 0; i < 8; ++i)
            __builtin_amdgcn_global_load_lds((gu32*)(wsrc + i * 4096),
                                             (lu32*)(dst0 + i * 4096), 16, 0, 0);
    }

    int cur = 0;
    for (int ch = 0; ch < 64; ++ch) {
        if (ch < 63) {
            const unsigned short* src = wsrc + (size_t)(ch + 1) * 32768;
            unsigned short* dst = cur ? dst0 : dst1;
            #pragma unroll
            for (int i = 0; i < 8; ++i)
                __builtin_amdgcn_global_load_lds((gu32*)(src + i * 4096),
                                                 (lu32*)(dst + i * 4096), 16, 0, 0);
            asm volatile("s_waitcnt vmcnt(8)" ::: "memory");
        } else {
            asm volatile("s_waitcnt vmcnt(0)" ::: "memory");
        }
        __builtin_amdgcn_s_barrier();
        __builtin_amdgcn_sched_barrier(0);

        f32x4 a0 = {0.f,0.f,0.f,0.f}, a1 = a0, a2 = a0, a3 = a0;

        #pragma unroll
        for (int ks = 0; ks < 8; ++ks) {
            const int slot = ks * 4 + lk;
            const bf16x8* Bh = reinterpret_cast<const bf16x8*>(&Bbuf[cur][0][slot][0][0]);
            const bf16x8* Bl = reinterpret_cast<const bf16x8*>(&Bbuf[cur][1][slot][0][0]);
            bf16x8 bh, bl;
            bh = Bh[lc];      bl = Bl[lc];
            a0 = __builtin_amdgcn_mfma_f32_16x16x32_bf16(ah[ks], bh, a0, 0, 0, 0);
            a0 = __builtin_amdgcn_mfma_f32_16x16x32_bf16(ah[ks], bl, a0, 0, 0, 0);
            a0 = __builtin_amdgcn_mfma_f32_16x16x32_bf16(al[ks], bh, a0, 0, 0, 0);
            bh = Bh[16 + lc]; bl = Bl[16 + lc];
            a1 = __builtin_amdgcn_mfma_f32_16x16x32_bf16(ah[ks], bh, a1, 0, 0, 0);
            a1 = __builtin_amdgcn_mfma_f32_16x16x32_bf16(ah[ks], bl, a1, 0, 0, 0);
            a1 = __builtin_amdgcn_mfma_f32_16x16x32_bf16(al[ks], bh, a1, 0, 0, 0);
            bh = Bh[32 + lc]; bl = Bl[32 + lc];
            a2 = __builtin_amdgcn_mfma_f32_16x16x32_bf16(ah[ks], bh, a2, 0, 0, 0);
            a2 = __builtin_amdgcn_mfma_f32_16x16x32_bf16(ah[ks], bl, a2, 0, 0, 0);
            a2 = __builtin_amdgcn_mfma_f32_16x16x32_bf16(al[ks], bh, a2, 0, 0, 0);
            bh = Bh[48 + lc]; bl = Bl[48 + lc];
            a3 = __builtin_amdgcn_mfma_f32_16x16x32_bf16(ah[ks], bh, a3, 0, 0, 0);
            a3 = __builtin_amdgcn_mfma_f32_16x16x32_bf16(ah[ks], bl, a3, 0, 0, 0);
            a3 = __builtin_amdgcn_mfma_f32_16x16x32_bf16(al[ks], bh, a3, 0, 0, 0);
        }

        const int nb = half * 4096 + ch * 64 + lc;
        #pragma unroll
        for (int j = 0; j < 4; ++j) {
            float v;
            v = -2.0f * a0[j];
            if (v < m1[j]) { m2[j] = m1[j]; m1[j] = v; i1[j] = nb; }
            else if (v < m2[j]) m2[j] = v;
            v = -2.0f * a1[j];
            if (v < m1[j]) { m2[j] = m1[j]; m1[j] = v; i1[j] = nb + 16; }
            else if (v < m2[j]) m2[j] = v;
            v = -2.0f * a2[j];
            if (v < m1[j]) { m2[j] = m1[j]; m1[j] = v; i1[j] = nb + 32; }
            else if (v < m2[j]) m2[j] = v;
            v = -2.0f * a3[j];
            if (v < m1[j]) { m2[j] = m1[j]; m1[j] = v; i1[j] = nb + 48; }
            else if (v < m2[j]) m2[j] = v;
        }

        __builtin_amdgcn_sched_barrier(0);
        __builtin_amdgcn_s_barrier();
        cur ^= 1;
    }

    // reduce across the 16 code-lanes of each row-group (ties -> smaller idx)
    #pragma unroll
    for (int off = 1; off < 16; off <<= 1) {
        #pragma unroll
        for (int j = 0; j < 4; ++j) {
            float om1 = __shfl_xor(m1[j], off, 64);
            float om2 = __shfl_xor(m2[j], off, 64);
            int   oi  = __shfl_xor(i1[j], off, 64);
            if (om1 < m1[j] || (om1 == m1[j] && oi < i1[j])) {
                m2[j] = fminf(m1[j], om2); m1[j] = om1; i1[j] = oi;
            } else {
                m2[j] = fminf(om1, m2[j]);
            }
        }
    }
    if (lc == 0) {
        #pragma unroll
        for (int j = 0; j < 4; ++j) {
            const int row = r0 + wv * 16 + lk * 4 + j;   // C row = (lane>>4)*4+j
            pm1[half * BT + row] = m1[j];
            pm2[half * BT + row] = m2[j];
            pi1[half * BT + row] = i1[j];
        }
    }
}

// merge the two code-halves per row; flag near-ties for refine
__global__ void merge_kernel(const float* __restrict__ pm1,
                             const float* __restrict__ pm2,
                             const int* __restrict__ pi1,
                             int* __restrict__ idx_out,
                             int* __restrict__ counter,
                             int* __restrict__ list) {
    const int r = blockIdx.x * 256 + threadIdx.x;
    float a1 = pm1[r], a2 = pm2[r]; int ai = pi1[r];
    float b1 = pm1[BT + r], b2 = pm2[BT + r]; int bi = pi1[BT + r];
    float f1, f2; int fi;
    if (b1 < a1 || (b1 == a1 && bi < ai)) { f1 = b1; fi = bi; f2 = fminf(a1, b2); }
    else                                  { f1 = a1; fi = ai; f2 = fminf(b1, a2); }
    idx_out[r] = fi;
    if (f2 - f1 < MARGIN) {
        int p = atomicAdd(counter, 1);
        list[p] = r;
    }
}

// ================= SHARED (refine / gather) =================

// refine v4: coalesced wave scan with 4 codes in flight (round-18's v3 was
// latency-serialized on the 6-level shfl chain: 1 code/iter = zero ILP).
// 4 independent load+reduce chains hide the ds_bpermute latency. Phase B
// (exact f64 on candidates within min+1e-3, lowest-index tie-break) unchanged.
__global__ void refine_kernel(const float* __restrict__ z,
                              const float* __restrict__ w,
                              const int* __restrict__ counter,
                              const int* __restrict__ list,
                              int* __restrict__ idx_out) {
    __shared__ double zn_s[256];
    __shared__ float  znf[256];
    __shared__ float  dist[NB];      // 32 KB
    __shared__ double rv[256];
    __shared__ int    ri[256];
    __shared__ float  fm[256];
    const int t = threadIdx.x;
    const int lane = t & 63;
    const int wv = t >> 6;           // 4 waves
    const int cnt = *counter;
    for (int item = blockIdx.x; item < cnt; item += gridDim.x) {
        const int row = list[item];
        double zv = (double)z[(size_t)row * DD + t];
        __syncthreads();
        rv[t] = zv * zv;
        __syncthreads();
        for (int s = 128; s; s >>= 1) { if (t < s) rv[t] += rv[t + s]; __syncthreads(); }
        double norm = sqrt(rv[0]);
        if (norm < 1e-12) norm = 1e-12;
        __syncthreads();
        zn_s[t] = zv / norm;
        znf[t] = (float)(zv / norm);
        __syncthreads();

        // lane-resident zn fragment (constant across codes)
        const float4 zn4 = *reinterpret_cast<const float4*>(&znf[lane * 4]);

        // ---- phase A: coalesced scan, 4 codes per wave-iteration (ILP) ----
        for (int n0 = wv * 4; n0 < NB; n0 += 16) {
            float d[4];
            #pragma unroll
            for (int i = 0; i < 4; ++i) {
                float4 v = *reinterpret_cast<const float4*>(
                    w + (size_t)(n0 + i) * DD + lane * 4);
                d[i] = (v.x * v.x + v.y * v.y + v.z * v.z + v.w * v.w)
                     - 2.f * (v.x * zn4.x + v.y * zn4.y + v.z * zn4.z + v.w * zn4.w);
            }
            #pragma unroll
            for (int off = 32; off; off >>= 1) {
                #pragma unroll
                for (int i = 0; i < 4; ++i) d[i] += __shfl_down(d[i], off, 64);
            }
            if (lane == 0) {
                dist[n0]     = d[0];
                dist[n0 + 1] = d[1];
                dist[n0 + 2] = d[2];
                dist[n0 + 3] = d[3];
            }
        }
        __syncthreads();

        // ---- block min of dist ----
        float best = INFINITY;
        #pragma unroll
        for (int j = 0; j < NB / 256; ++j) best = fminf(best, dist[t + 256 * j]);
        fm[t] = best;
        __syncthreads();
        for (int s = 128; s; s >>= 1) { if (t < s) fm[t] = fminf(fm[t], fm[t + s]); __syncthreads(); }
        const float thresh = fm[0] + 1e-3f;

        // ---- phase B: exact f64 on candidates only ----
        double bv = INFINITY; int bi = 0x7fffffff;
        for (int j = 0; j < NB / 256; ++j) {
            const int n = t + 256 * j;
            if (dist[n] <= thresh) {
                const float* wr = w + (size_t)n * DD;
                double dot = 0.0, wsqd = 0.0;
                for (int k = 0; k < DD; ++k) {
                    double wvv = (double)wr[k];
                    dot  += zn_s[k] * wvv;
                    wsqd += wvv * wvv;
                }
                double d2 = wsqd - 2.0 * dot;
                if (d2 < bv || (d2 == bv && n < bi)) { bv = d2; bi = n; }
            }
        }
        __syncthreads();
        rv[t] = bv; ri[t] = bi;
        __syncthreads();
        for (int s = 128; s; s >>= 1) {
            if (t < s) {
                if (rv[t + s] < rv[t] || (rv[t + s] == rv[t] && ri[t + s] < ri[t])) {
                    rv[t] = rv[t + s]; ri[t] = ri[t + s];
                }
            }
            __syncthreads();
        }
        if (t == 0) idx_out[row] = ri[0];
        __syncthreads();
    }
}

__global__ void gather_kernel(const float* __restrict__ w,
                              const int* __restrict__ idx,
                              float* __restrict__ out) {
    const int t = threadIdx.x;
    const int blk = blockIdx.x;
    const int row = blk * 8 + (t >> 5);
    const int lane = t & 31;
    int n = idx[row];
    if ((unsigned)n >= (unsigned)NB) n = 0;
    const float4* src = reinterpret_cast<const float4*>(w + (size_t)n * DD + lane * 8);
    float4 v0 = src[0], v1 = src[1];
    float4* dst = reinterpret_cast<float4*>(out + (size_t)row * DD + lane * 8);
    dst[0] = v0;
    dst[1] = v1;
    if (t < 8) {
        int r2 = blk * 8 + t;
        out[(size_t)BT * DD + r2] = (float)idx[r2];
    }
}

// ================= FALLBACK (round-4, validated) =================

__global__ void rownorm_kernel(const float* __restrict__ x, int rows,
                               float* __restrict__ out, int mode) {
    int row  = blockIdx.x * 4 + (threadIdx.x >> 6);
    int lane = threadIdx.x & 63;
    if (row >= rows) return;
    const float4 v = *reinterpret_cast<const float4*>(x + (size_t)row * DD + lane * 4);
    double s = (double)v.x * v.x + (double)v.y * v.y + (double)v.z * v.z + (double)v.w * v.w;
    #pragma unroll
    for (int off = 32; off; off >>= 1) s += __shfl_down(s, off, 64);
    if (lane == 0) {
        if (mode == 0) {
            double n = sqrt(s);
            if (n < 1e-12) n = 1e-12;
            out[row] = (float)(1.0 / n);
        } else {
            out[row] = (float)s;
        }
    }
}

__launch_bounds__(256, 1)
__global__ void argmin_mfma(const float* __restrict__ z,
                            const float* __restrict__ w,
                            const float* __restrict__ invn,
                            const float* __restrict__ wsq,
                            int* __restrict__ idx_out,
                            int* __restrict__ counter,
                            int* __restrict__ list) {
    __shared__ unsigned short Ahi[64][256];
    __shared__ unsigned short Alo[64][256];
    __shared__ unsigned short Bhi[64][256];
    __shared__ unsigned short Blo[64][256];
    __shared__ float wsq_s[64];
    __shared__ float red_m1[2][64];
    __shared__ float red_m2[2][64];
    __shared__ int   red_i1[2][64];

    typedef float f32x16 __attribute__((ext_vector_type(16)));
    const int t    = threadIdx.x;
    const int lane = t & 63;
    const int wvv  = t >> 6;
    const int wy = wvv >> 1, wx = wvv & 1;
    const int l5 = lane >> 5, lq = lane & 31;
    const int r0 = blockIdx.x * 64;

    {
        const int ar = t >> 2;
        const int sbase = (t & 3) * 8;
        const float* zr = z + (size_t)(r0 + ar) * DD + (t & 3) * 64;
        #pragma unroll
        for (int g = 0; g < 8; ++g) {
            float4 v0 = reinterpret_cast<const float4*>(zr)[2 * g];
            float4 v1 = reinterpret_cast<const float4*>(zr)[2 * g + 1];
            u16x8 hv, lv;
            split8(v0, v1, hv, lv);
            int slot = (sbase + g) ^ (ar & 7);
            *reinterpret_cast<u16x8*>(&Ahi[ar][slot * 8]) = hv;
            *reinterpret_cast<u16x8*>(&Alo[ar][slot * 8]) = lv;
        }
    }

    float twoinv[16];
    #pragma unroll
    for (int r = 0; r < 16; ++r)
        twoinv[r] = 2.0f * invn[r0 + wy * 32 + (r & 3) + 8 * (r >> 2) + 4 * l5];

    float m1[16], m2[16]; int i1[16];
    #pragma unroll
    for (int r = 0; r < 16; ++r) { m1[r] = INFINITY; m2[r] = INFINITY; i1[r] = 0; }

    const int cc = t >> 2;
    const int sbase = (t & 3) * 8;
    float4 pre[16];
    {
        const float* wb = w + (size_t)cc * DD + (t & 3) * 64;
        #pragma unroll
        for (int q = 0; q < 16; ++q) pre[q] = reinterpret_cast<const float4*>(wb)[q];
    }
    float wsq_pre = (t < 64) ? wsq[t] : 0.f;

    const int am = wy * 32 + lq;
    const int bn = wx * 32 + lq;
    const int sxor = lq & 7;

    for (int ch = 0; ch < 128; ++ch) {
        __syncthreads();
        #pragma unroll
        for (int g = 0; g < 8; ++g) {
            u16x8 hv, lv;
            split8(pre[2 * g], pre[2 * g + 1], hv, lv);
            int slot = (sbase + g) ^ (cc & 7);
            *reinterpret_cast<u16x8*>(&Bhi[cc][slot * 8]) = hv;
            *reinterpret_cast<u16x8*>(&Blo[cc][slot * 8]) = lv;
        }
        if (t < 64) wsq_s[t] = wsq_pre;
        __syncthreads();

        if (ch < 127) {
            const float* wb = w + (size_t)((ch + 1) * 64 + cc) * DD + (t & 3) * 64;
            #pragma unroll
            for (int q = 0; q < 16; ++q) pre[q] = reinterpret_cast<const float4*>(wb)[q];
            if (t < 64) wsq_pre = wsq[(ch + 1) * 64 + t];
        }

        f32x16 acc0, acc1;
        #pragma unroll
        for (int r = 0; r < 16; ++r) { acc0[r] = 0.f; acc1[r] = 0.f; }

        #pragma unroll
        for (int s = 0; s < 16; ++s) {
            const int sl = (2 * s + l5) ^ sxor;
            bf16x8 ah = *reinterpret_cast<const bf16x8*>(&Ahi[am][sl * 8]);
            bf16x8 al = *reinterpret_cast<const bf16x8*>(&Alo[am][sl * 8]);
            bf16x8 bh = *reinterpret_cast<const bf16x8*>(&Bhi[bn][sl * 8]);
            bf16x8 bl = *reinterpret_cast<const bf16x8*>(&Blo[bn][sl * 8]);
            acc0 = __builtin_amdgcn_mfma_f32_32x32x16_bf16(ah, bh, acc0, 0, 0, 0);
            acc1 = __builtin_amdgcn_mfma_f32_32x32x16_bf16(ah, bl, acc1, 0, 0, 0);
            acc0 = __builtin_amdgcn_mfma_f32_32x32x16_bf16(al, bh, acc0, 0, 0, 0);
        }

        const float wq = wsq_s[bn];
        const int nidx = ch * 64 + bn;
        #pragma unroll
        for (int r = 0; r < 16; ++r) {
            float v = wq - twoinv[r] * (acc0[r] + acc1[r]);
            if (v < m1[r]) { m2[r] = m1[r]; m1[r] = v; i1[r] = nidx; }
            else if (v < m2[r]) m2[r] = v;
        }
    }

    #pragma unroll
    for (int off = 1; off < 32; off <<= 1) {
        #pragma unroll
        for (int r = 0; r < 16; ++r) {
            float om1 = __shfl_xor(m1[r], off, 64);
            float om2 = __shfl_xor(m2[r], off, 64);
            int   oi  = __shfl_xor(i1[r], off, 64);
            if (om1 < m1[r] || (om1 == m1[r] && oi < i1[r])) {
                m2[r] = fminf(m1[r], om2); m1[r] = om1; i1[r] = oi;
            } else {
                m2[r] = fminf(om1, m2[r]);
            }
        }
    }
    if (lq == 0) {
        #pragma unroll
        for (int r = 0; r < 16; ++r) {
            int ml = wy * 32 + (r & 3) + 8 * (r >> 2) + 4 * l5;
            red_m1[wx][ml] = m1[r];
            red_m2[wx][ml] = m2[r];
            red_i1[wx][ml] = i1[r];
        }
    }
    __syncthreads();
    if (t < 64) {
        float a1 = red_m1[0][t], a2 = red_m2[0][t]; int ai = red_i1[0][t];
        float b1 = red_m1[1][t], b2 = red_m2[1][t]; int bi = red_i1[1][t];
        float f1, f2; int fi;
        if (b1 < a1 || (b1 == a1 && bi < ai)) { f1 = b1; fi = bi; f2 = fminf(a1, b2); }
        else                                  { f1 = a1; fi = ai; f2 = fminf(b1, a2); }
        idx_out[r0 + t] = fi;
        if (f2 - f1 < MARGIN) {
            int p = atomicAdd(counter, 1);
            list[p] = r0 + t;
        }
    }
}

extern "C" void kernel_launch(void* const* d_in, const int* in_sizes, int n_in,
                              void* d_out, int out_size, void* d_ws, size_t ws_size,
                              hipStream_t stream) {
    const float* z = (const float*)d_in[0];
    const float* w = (const float*)d_in[1];
    float* out = (float*)d_out;
    char* ws = (char*)d_ws;

    if (ws_size >= W2_NEED) {
        unsigned short* wtile = (unsigned short*)(ws + W2_WTILE);
        float* pm1 = (float*)(ws + W2_PM1);
        float* pm2 = (float*)(ws + W2_PM2);
        int*   pi1 = (int*)(ws + W2_PI1);
        int*   idx = (int*)(ws + W2_IDX);
        int*   cnt = (int*)(ws + W2_CNT);
        int*   list = (int*)(ws + W2_LIST);
        u16x8* zt = (u16x8*)d_out;     // z_q region doubles as zt scratch

        hipMemsetAsync(cnt, 0, 4, stream);
        prep_kernel<<<640, 256, 0, stream>>>(z, w, zt, wtile);
        argmin2<<<256, 512, 0, stream>>>(zt, wtile, pm1, pm2, pi1);
        merge_kernel<<<64, 256, 0, stream>>>(pm1, pm2, pi1, idx, cnt, list);
        refine_kernel<<<512, 256, 0, stream>>>(z, w, cnt, list, idx);
        gather_kernel<<<BT / 8, 256, 0, stream>>>(w, idx, out);
    } else {
        float* inv  = (float*)(ws + WS_INV);
        float* wsq  = (float*)(ws + WS_WSQ);
        int*   idx  = (int*)(ws + WS_IDX);
        int*   cnt  = (int*)(ws + WS_CNT);
        int*   list = (int*)(ws + WS_LIST);

        hipMemsetAsync(cnt, 0, 4, stream);
        rownorm_kernel<<<BT / 4, 256, 0, stream>>>(z, BT, inv, 0);
        rownorm_kernel<<<NB / 4, 256, 0, stream>>>(w, NB, wsq, 1);
        argmin_mfma<<<BT / 64, 256, 0, stream>>>(z, w, inv, wsq, idx, cnt, list);
        refine_kernel<<<64, 256, 0, stream>>>(z, w, cnt, list, idx);
        gather_kernel<<<BT / 8, 256, 0, stream>>>(w, idx, out);
    }
}

// Round 20
// 326.728 us; speedup vs baseline: 3.6758x; 1.8429x over previous
//
#include <hip/hip_runtime.h>
#include <hip/hip_bf16.h>

#define BT 16384
#define NB 8192
#define DD 256
#define MARGIN 2e-4f
#define MAXITEM 4096

typedef short bf16x8 __attribute__((ext_vector_type(8)));
typedef unsigned short u16x8 __attribute__((ext_vector_type(8)));
typedef float f32x4 __attribute__((ext_vector_type(4)));
typedef __attribute__((address_space(1))) unsigned int gu32;
typedef __attribute__((address_space(3))) unsigned int lu32;

// ---- fast-path ws layout (bytes) ----
#define W2_WTILE 0
#define W2_PM1   (8*1024*1024)
#define W2_PM2   (W2_PM1 + 2*BT*4)
#define W2_PI1   (W2_PM2 + 2*BT*4)
#define W2_IDX   (W2_PI1 + 2*BT*4)
#define W2_CNT   (W2_IDX + BT*4)
#define W2_LIST  (W2_CNT + 256)
#define W2_PBV   (W2_LIST + BT*4)
#define W2_PBI   (W2_PBV + MAXITEM*16*8)
#define W2_NEED  ((size_t)(W2_PBI + MAXITEM*16*4))

// ---- fallback ws layout (round-4, validated) ----
#define WS_INV  0
#define WS_WSQ  (BT*4)
#define WS_IDX  (WS_WSQ + NB*4)
#define WS_CNT  (WS_IDX + BT*4)
#define WS_LIST (WS_CNT + 64)

__device__ __forceinline__ unsigned int f2bf(float f) {
    unsigned int u = __float_as_uint(f);
    return (u + 0x7FFFu + ((u >> 16) & 1u)) >> 16;
}

__device__ __forceinline__ void split8(const float4 a, const float4 b, u16x8 &hv, u16x8 &lv) {
    float xs[8] = {a.x, a.y, a.z, a.w, b.x, b.y, b.z, b.w};
    #pragma unroll
    for (int i = 0; i < 8; ++i) {
        unsigned int h = f2bf(xs[i]);
        hv[i] = (unsigned short)h;
        lv[i] = (unsigned short)f2bf(xs[i] - __uint_as_float(h << 16));
    }
}

// ================= FAST PATH =================

// Fused prep: blocks 0..511 = zsplit (normalize+split z), 512..639 = wsplit.
__global__ void prep_kernel(const float* __restrict__ z,
                            const float* __restrict__ w,
                            u16x8* __restrict__ zt,
                            unsigned short* __restrict__ wtile) {
    const int t = threadIdx.x;
    if (blockIdx.x >= 512) {
        const int ch = blockIdx.x - 512;
        const int c  = t >> 2;
        const int q  = t & 3;
        const float* wr = w + (size_t)(ch * 64 + c) * DD + q * 64;
        unsigned short* base = wtile + (size_t)ch * 32768;
        #pragma unroll
        for (int g = 0; g < 8; ++g) {
            float4 v0 = reinterpret_cast<const float4*>(wr)[2 * g];
            float4 v1 = reinterpret_cast<const float4*>(wr)[2 * g + 1];
            u16x8 hv, lv;
            split8(v0, v1, hv, lv);
            const int slot = q * 8 + g;
            *reinterpret_cast<u16x8*>(base + ((size_t)slot * 64 + c) * 8) = hv;
            *reinterpret_cast<u16x8*>(base + ((size_t)(32 + slot) * 64 + c) * 8) = lv;
        }
        return;
    }
    __shared__ float inv_s[32];
    const int rt = blockIdx.x;
    {
        const int rl = t >> 3, sub = t & 7;
        const float4* zr = reinterpret_cast<const float4*>(
            z + (size_t)(rt * 32 + rl) * DD + sub * 32);
        double s = 0.0;
        #pragma unroll
        for (int i = 0; i < 8; ++i) {
            float4 v = zr[i];
            s += (double)v.x*v.x + (double)v.y*v.y + (double)v.z*v.z + (double)v.w*v.w;
        }
        s += __shfl_xor(s, 1, 64);
        s += __shfl_xor(s, 2, 64);
        s += __shfl_xor(s, 4, 64);
        if (sub == 0) {
            double n = sqrt(s);
            if (n < 1e-12) n = 1e-12;
            inv_s[rl] = (float)(1.0 / n);
        }
    }
    __syncthreads();
    const int sg = t >> 6, l = t & 63;
    const int tau  = rt * 2 + (sg >> 1);
    const int rowl = (sg >> 1) * 16 + (l & 15);
    const int row  = rt * 32 + rowl;
    const float inv = inv_s[rowl];
    #pragma unroll
    for (int ksi = 0; ksi < 4; ++ksi) {
        const int ks = (sg & 1) * 4 + ksi;
        const int k0 = ks * 32 + (l >> 4) * 8;
        float4 a = *reinterpret_cast<const float4*>(z + (size_t)row * DD + k0);
        float4 b = *reinterpret_cast<const float4*>(z + (size_t)row * DD + k0 + 4);
        a.x *= inv; a.y *= inv; a.z *= inv; a.w *= inv;
        b.x *= inv; b.y *= inv; b.z *= inv; b.w *= inv;
        u16x8 hv, lv;
        split8(a, b, hv, lv);
        const size_t o = ((size_t)tau * 8 + ks) * 64 + l;
        zt[o] = hv;
        zt[524288 + o] = lv;
    }
}

// Fused MFMA argmin, 16x16x32 (round-15 validated: 257us, no spill).
__launch_bounds__(512, 1)
__global__ void argmin2(const u16x8* __restrict__ zt,
                        const unsigned short* __restrict__ wtile,
                        float* __restrict__ pm1,
                        float* __restrict__ pm2,
                        int* __restrict__ pi1) {
    __shared__ __align__(16) unsigned short Bbuf[2][2][32][64][8]; // 128 KB
    const int t = threadIdx.x, lane = t & 63, wv = t >> 6;
    const int b = blockIdx.x;
    const int rb   = b >> 1;
    const int half = b & 1;
    const int r0   = rb * 128;
    const int tau  = rb * 8 + wv;
    const int lc = lane & 15;
    const int lk = lane >> 4;

    const bf16x8* zf = reinterpret_cast<const bf16x8*>(zt);
    bf16x8 ah[8], al[8];
    #pragma unroll
    for (int ks = 0; ks < 8; ++ks) {
        const size_t o = ((size_t)tau * 8 + ks) * 64 + lane;
        ah[ks] = zf[o];
        al[ks] = zf[524288 + o];
    }

    float m1[4], m2[4]; int i1[4];
    #pragma unroll
    for (int j = 0; j < 4; ++j) { m1[j] = INFINITY; m2[j] = INFINITY; i1[j] = 0; }

    const unsigned short* wsrc = wtile + (size_t)half * 2097152 + (size_t)t * 8;
    unsigned short* dst0 = &Bbuf[0][0][0][0][0] + (size_t)t * 8;
    unsigned short* dst1 = &Bbuf[1][0][0][0][0] + (size_t)t * 8;

    {
        #pragma unroll
        for (int i = 0; i < 8; ++i)
            __builtin_amdgcn_global_load_lds((gu32*)(wsrc + i * 4096),
                                             (lu32*)(dst0 + i * 4096), 16, 0, 0);
    }

    int cur = 0;
    for (int ch = 0; ch < 64; ++ch) {
        if (ch < 63) {
            const unsigned short* src = wsrc + (size_t)(ch + 1) * 32768;
            unsigned short* dst = cur ? dst0 : dst1;
            #pragma unroll
            for (int i = 0; i < 8; ++i)
                __builtin_amdgcn_global_load_lds((gu32*)(src + i * 4096),
                                                 (lu32*)(dst + i * 4096), 16, 0, 0);
            asm volatile("s_waitcnt vmcnt(8)" ::: "memory");
        } else {
            asm volatile("s_waitcnt vmcnt(0)" ::: "memory");
        }
        __builtin_amdgcn_s_barrier();
        __builtin_amdgcn_sched_barrier(0);

        f32x4 a0 = {0.f,0.f,0.f,0.f}, a1 = a0, a2 = a0, a3 = a0;

        #pragma unroll
        for (int ks = 0; ks < 8; ++ks) {
            const int slot = ks * 4 + lk;
            const bf16x8* Bh = reinterpret_cast<const bf16x8*>(&Bbuf[cur][0][slot][0][0]);
            const bf16x8* Bl = reinterpret_cast<const bf16x8*>(&Bbuf[cur][1][slot][0][0]);
            bf16x8 bh, bl;
            bh = Bh[lc];      bl = Bl[lc];
            a0 = __builtin_amdgcn_mfma_f32_16x16x32_bf16(ah[ks], bh, a0, 0, 0, 0);
            a0 = __builtin_amdgcn_mfma_f32_16x16x32_bf16(ah[ks], bl, a0, 0, 0, 0);
            a0 = __builtin_amdgcn_mfma_f32_16x16x32_bf16(al[ks], bh, a0, 0, 0, 0);
            bh = Bh[16 + lc]; bl = Bl[16 + lc];
            a1 = __builtin_amdgcn_mfma_f32_16x16x32_bf16(ah[ks], bh, a1, 0, 0, 0);
            a1 = __builtin_amdgcn_mfma_f32_16x16x32_bf16(ah[ks], bl, a1, 0, 0, 0);
            a1 = __builtin_amdgcn_mfma_f32_16x16x32_bf16(al[ks], bh, a1, 0, 0, 0);
            bh = Bh[32 + lc]; bl = Bl[32 + lc];
            a2 = __builtin_amdgcn_mfma_f32_16x16x32_bf16(ah[ks], bh, a2, 0, 0, 0);
            a2 = __builtin_amdgcn_mfma_f32_16x16x32_bf16(ah[ks], bl, a2, 0, 0, 0);
            a2 = __builtin_amdgcn_mfma_f32_16x16x32_bf16(al[ks], bh, a2, 0, 0, 0);
            bh = Bh[48 + lc]; bl = Bl[48 + lc];
            a3 = __builtin_amdgcn_mfma_f32_16x16x32_bf16(ah[ks], bh, a3, 0, 0, 0);
            a3 = __builtin_amdgcn_mfma_f32_16x16x32_bf16(ah[ks], bl, a3, 0, 0, 0);
            a3 = __builtin_amdgcn_mfma_f32_16x16x32_bf16(al[ks], bh, a3, 0, 0, 0);
        }

        const int nb = half * 4096 + ch * 64 + lc;
        #pragma unroll
        for (int j = 0; j < 4; ++j) {
            float v;
            v = -2.0f * a0[j];
            if (v < m1[j]) { m2[j] = m1[j]; m1[j] = v; i1[j] = nb; }
            else if (v < m2[j]) m2[j] = v;
            v = -2.0f * a1[j];
            if (v < m1[j]) { m2[j] = m1[j]; m1[j] = v; i1[j] = nb + 16; }
            else if (v < m2[j]) m2[j] = v;
            v = -2.0f * a2[j];
            if (v < m1[j]) { m2[j] = m1[j]; m1[j] = v; i1[j] = nb + 32; }
            else if (v < m2[j]) m2[j] = v;
            v = -2.0f * a3[j];
            if (v < m1[j]) { m2[j] = m1[j]; m1[j] = v; i1[j] = nb + 48; }
            else if (v < m2[j]) m2[j] = v;
        }

        __builtin_amdgcn_sched_barrier(0);
        __builtin_amdgcn_s_barrier();
        cur ^= 1;
    }

    #pragma unroll
    for (int off = 1; off < 16; off <<= 1) {
        #pragma unroll
        for (int j = 0; j < 4; ++j) {
            float om1 = __shfl_xor(m1[j], off, 64);
            float om2 = __shfl_xor(m2[j], off, 64);
            int   oi  = __shfl_xor(i1[j], off, 64);
            if (om1 < m1[j] || (om1 == m1[j] && oi < i1[j])) {
                m2[j] = fminf(m1[j], om2); m1[j] = om1; i1[j] = oi;
            } else {
                m2[j] = fminf(om1, m2[j]);
            }
        }
    }
    if (lc == 0) {
        #pragma unroll
        for (int j = 0; j < 4; ++j) {
            const int row = r0 + wv * 16 + lk * 4 + j;
            pm1[half * BT + row] = m1[j];
            pm2[half * BT + row] = m2[j];
            pi1[half * BT + row] = i1[j];
        }
    }
}

// merge the two code-halves per row; flag near-ties for refine
__global__ void merge_kernel(const float* __restrict__ pm1,
                             const float* __restrict__ pm2,
                             const int* __restrict__ pi1,
                             int* __restrict__ idx_out,
                             int* __restrict__ counter,
                             int* __restrict__ list) {
    const int r = blockIdx.x * 256 + threadIdx.x;
    float a1 = pm1[r], a2 = pm2[r]; int ai = pi1[r];
    float b1 = pm1[BT + r], b2 = pm2[BT + r]; int bi = pi1[BT + r];
    float f1, f2; int fi;
    if (b1 < a1 || (b1 == a1 && bi < ai)) { f1 = b1; fi = bi; f2 = fminf(a1, b2); }
    else                                  { f1 = a1; fi = ai; f2 = fminf(b1, a2); }
    idx_out[r] = fi;
    if (f2 - f1 < MARGIN) {
        int p = atomicAdd(counter, 1);
        list[p] = r;
    }
}

// ================= SHARED (refine / gather) =================

// refine v5: item x 16-segment decomposition. Each block handles one
// (item, 512-code segment) pair: coalesced f32 scan (4-code ILP), local
// threshold min+1e-3, exact f64 on local candidates (local argmin always
// qualifies), per-segment (f64,idx) partial -> refine2 merges. Identical
// arbiter to validated single-block version (segments partition codes).
__global__ void refine_kernel(const float* __restrict__ z,
                              const float* __restrict__ w,
                              const int* __restrict__ counter,
                              const int* __restrict__ list,
                              int* __restrict__ idx_out,
                              double* __restrict__ pbv,
                              int* __restrict__ pbi) {
    __shared__ double zn_s[256];
    __shared__ float  znf[256];
    __shared__ float  dist[512];
    __shared__ double rv[256];
    __shared__ int    ri[256];
    __shared__ float  fm[256];
    const int t = threadIdx.x;
    const int lane = t & 63;
    const int wv = t >> 6;
    const int cnt = *counter;
    const int nit = (cnt < MAXITEM) ? cnt : MAXITEM;
    const long long npair = (long long)nit * 16;

    for (long long p = blockIdx.x; p < npair; p += gridDim.x) {
        const int item = (int)(p >> 4), seg = (int)(p & 15);
        const int row = list[item];
        double zv = (double)z[(size_t)row * DD + t];
        __syncthreads();
        rv[t] = zv * zv;
        __syncthreads();
        for (int s = 128; s; s >>= 1) { if (t < s) rv[t] += rv[t + s]; __syncthreads(); }
        double norm = sqrt(rv[0]);
        if (norm < 1e-12) norm = 1e-12;
        __syncthreads();
        zn_s[t] = zv / norm;
        znf[t] = (float)(zv / norm);
        __syncthreads();

        const float4 zn4 = *reinterpret_cast<const float4*>(&znf[lane * 4]);
        const int nbase = seg * 512;

        // phase A: 512 codes, 4 waves x (4 codes in flight)
        for (int o = wv * 4; o < 512; o += 16) {
            float d[4];
            #pragma unroll
            for (int i = 0; i < 4; ++i) {
                float4 v = *reinterpret_cast<const float4*>(
                    w + (size_t)(nbase + o + i) * DD + lane * 4);
                d[i] = (v.x * v.x + v.y * v.y + v.z * v.z + v.w * v.w)
                     - 2.f * (v.x * zn4.x + v.y * zn4.y + v.z * zn4.z + v.w * zn4.w);
            }
            #pragma unroll
            for (int off = 32; off; off >>= 1) {
                #pragma unroll
                for (int i = 0; i < 4; ++i) d[i] += __shfl_down(d[i], off, 64);
            }
            if (lane == 0) {
                dist[o] = d[0]; dist[o + 1] = d[1];
                dist[o + 2] = d[2]; dist[o + 3] = d[3];
            }
        }
        __syncthreads();

        // local min over the 512 distances
        fm[t] = fminf(dist[t], dist[t + 256]);
        __syncthreads();
        for (int s = 128; s; s >>= 1) { if (t < s) fm[t] = fminf(fm[t], fm[t + s]); __syncthreads(); }
        const float thresh = fm[0] + 1e-3f;

        // phase B: exact f64 on local candidates (2 codes per thread)
        double bv = INFINITY; int bi = 0x7fffffff;
        #pragma unroll
        for (int j = 0; j < 2; ++j) {
            const int nl = t + j * 256;
            if (dist[nl] <= thresh) {
                const int n = nbase + nl;
                const float* wr = w + (size_t)n * DD;
                double dot = 0.0, wsqd = 0.0;
                for (int k = 0; k < DD; ++k) {
                    double wvv = (double)wr[k];
                    dot  += zn_s[k] * wvv;
                    wsqd += wvv * wvv;
                }
                double d2 = wsqd - 2.0 * dot;
                if (d2 < bv || (d2 == bv && n < bi)) { bv = d2; bi = n; }
            }
        }
        __syncthreads();
        rv[t] = bv; ri[t] = bi;
        __syncthreads();
        for (int s = 128; s; s >>= 1) {
            if (t < s) {
                if (rv[t + s] < rv[t] || (rv[t + s] == rv[t] && ri[t + s] < ri[t])) {
                    rv[t] = rv[t + s]; ri[t] = ri[t + s];
                }
            }
            __syncthreads();
        }
        if (t == 0) { pbv[p] = rv[0]; pbi[p] = ri[0]; }
        __syncthreads();
    }

    // overflow items (>= MAXITEM): single-block full scan (validated v4 path)
    for (int item = MAXITEM + blockIdx.x; item < cnt; item += gridDim.x) {
        const int row = list[item];
        double zv = (double)z[(size_t)row * DD + t];
        __syncthreads();
        rv[t] = zv * zv;
        __syncthreads();
        for (int s = 128; s; s >>= 1) { if (t < s) rv[t] += rv[t + s]; __syncthreads(); }
        double norm = sqrt(rv[0]);
        if (norm < 1e-12) norm = 1e-12;
        __syncthreads();
        zn_s[t] = zv / norm;
        __syncthreads();
        double bv = INFINITY; int bi = 0x7fffffff;
        for (int n = t; n < NB; n += 256) {
            const float* wr = w + (size_t)n * DD;
            double dot = 0.0, wsqd = 0.0;
            for (int k = 0; k < DD; ++k) {
                double wvv = (double)wr[k];
                dot  += zn_s[k] * wvv;
                wsqd += wvv * wvv;
            }
            double d2 = wsqd - 2.0 * dot;
            if (d2 < bv || (d2 == bv && n < bi)) { bv = d2; bi = n; }
        }
        __syncthreads();
        rv[t] = bv; ri[t] = bi;
        __syncthreads();
        for (int s = 128; s; s >>= 1) {
            if (t < s) {
                if (rv[t + s] < rv[t] || (rv[t + s] == rv[t] && ri[t + s] < ri[t])) {
                    rv[t] = rv[t + s]; ri[t] = ri[t + s];
                }
            }
            __syncthreads();
        }
        if (t == 0) idx_out[row] = ri[0];
        __syncthreads();
    }
}

// merge the 16 per-segment partials of each item (same arbiter)
__global__ void refine2_kernel(const int* __restrict__ counter,
                               const int* __restrict__ list,
                               const double* __restrict__ pbv,
                               const int* __restrict__ pbi,
                               int* __restrict__ idx_out) {
    const int item = blockIdx.x * 256 + threadIdx.x;
    const int cnt = *counter;
    const int nit = (cnt < MAXITEM) ? cnt : MAXITEM;
    if (item >= nit) return;
    double bv = INFINITY; int bi = 0x7fffffff;
    #pragma unroll 4
    for (int s = 0; s < 16; ++s) {
        double v = pbv[(long long)item * 16 + s];
        int    i = pbi[(long long)item * 16 + s];
        if (v < bv || (v == bv && i < bi)) { bv = v; bi = i; }
    }
    idx_out[list[item]] = bi;
}

__global__ void gather_kernel(const float* __restrict__ w,
                              const int* __restrict__ idx,
                              float* __restrict__ out) {
    const int t = threadIdx.x;
    const int blk = blockIdx.x;
    const int row = blk * 8 + (t >> 5);
    const int lane = t & 31;
    int n = idx[row];
    if ((unsigned)n >= (unsigned)NB) n = 0;
    const float4* src = reinterpret_cast<const float4*>(w + (size_t)n * DD + lane * 8);
    float4 v0 = src[0], v1 = src[1];
    float4* dst = reinterpret_cast<float4*>(out + (size_t)row * DD + lane * 8);
    dst[0] = v0;
    dst[1] = v1;
    if (t < 8) {
        int r2 = blk * 8 + t;
        out[(size_t)BT * DD + r2] = (float)idx[r2];
    }
}

// ================= FALLBACK (round-4, validated) =================

__global__ void rownorm_kernel(const float* __restrict__ x, int rows,
                               float* __restrict__ out, int mode) {
    int row  = blockIdx.x * 4 + (threadIdx.x >> 6);
    int lane = threadIdx.x & 63;
    if (row >= rows) return;
    const float4 v = *reinterpret_cast<const float4*>(x + (size_t)row * DD + lane * 4);
    double s = (double)v.x * v.x + (double)v.y * v.y + (double)v.z * v.z + (double)v.w * v.w;
    #pragma unroll
    for (int off = 32; off; off >>= 1) s += __shfl_down(s, off, 64);
    if (lane == 0) {
        if (mode == 0) {
            double n = sqrt(s);
            if (n < 1e-12) n = 1e-12;
            out[row] = (float)(1.0 / n);
        } else {
            out[row] = (float)s;
        }
    }
}

__global__ void refine_full_kernel(const float* __restrict__ z,
                                   const float* __restrict__ w,
                                   const int* __restrict__ counter,
                                   const int* __restrict__ list,
                                   int* __restrict__ idx_out) {
    __shared__ double zn_s[256];
    __shared__ double rv[256];
    __shared__ int    ri[256];
    const int t = threadIdx.x;
    const int cnt = *counter;
    for (int item = blockIdx.x; item < cnt; item += gridDim.x) {
        const int row = list[item];
        double zv = (double)z[(size_t)row * DD + t];
        __syncthreads();
        rv[t] = zv * zv;
        __syncthreads();
        for (int s = 128; s; s >>= 1) { if (t < s) rv[t] += rv[t + s]; __syncthreads(); }
        double norm = sqrt(rv[0]);
        if (norm < 1e-12) norm = 1e-12;
        __syncthreads();
        zn_s[t] = zv / norm;
        __syncthreads();
        double bv = INFINITY; int bi = 0;
        for (int n = t; n < NB; n += 256) {
            double dot = 0.0, wsqd = 0.0;
            const float* wr = w + (size_t)n * DD;
            for (int k = 0; k < DD; ++k) {
                double wv = (double)wr[k];
                dot  += zn_s[k] * wv;
                wsqd += wv * wv;
            }
            double dist = wsqd - 2.0 * dot;
            if (dist < bv) { bv = dist; bi = n; }
        }
        __syncthreads();
        rv[t] = bv; ri[t] = bi;
        __syncthreads();
        for (int s = 128; s; s >>= 1) {
            if (t < s) {
                if (rv[t + s] < rv[t] || (rv[t + s] == rv[t] && ri[t + s] < ri[t])) {
                    rv[t] = rv[t + s]; ri[t] = ri[t + s];
                }
            }
            __syncthreads();
        }
        if (t == 0) idx_out[row] = ri[0];
        __syncthreads();
    }
}

__launch_bounds__(256, 1)
__global__ void argmin_mfma(const float* __restrict__ z,
                            const float* __restrict__ w,
                            const float* __restrict__ invn,
                            const float* __restrict__ wsq,
                            int* __restrict__ idx_out,
                            int* __restrict__ counter,
                            int* __restrict__ list) {
    __shared__ unsigned short Ahi[64][256];
    __shared__ unsigned short Alo[64][256];
    __shared__ unsigned short Bhi[64][256];
    __shared__ unsigned short Blo[64][256];
    __shared__ float wsq_s[64];
    __shared__ float red_m1[2][64];
    __shared__ float red_m2[2][64];
    __shared__ int   red_i1[2][64];

    typedef float f32x16 __attribute__((ext_vector_type(16)));
    const int t    = threadIdx.x;
    const int lane = t & 63;
    const int wvv  = t >> 6;
    const int wy = wvv >> 1, wx = wvv & 1;
    const int l5 = lane >> 5, lq = lane & 31;
    const int r0 = blockIdx.x * 64;

    {
        const int ar = t >> 2;
        const int sbase = (t & 3) * 8;
        const float* zr = z + (size_t)(r0 + ar) * DD + (t & 3) * 64;
        #pragma unroll
        for (int g = 0; g < 8; ++g) {
            float4 v0 = reinterpret_cast<const float4*>(zr)[2 * g];
            float4 v1 = reinterpret_cast<const float4*>(zr)[2 * g + 1];
            u16x8 hv, lv;
            split8(v0, v1, hv, lv);
            int slot = (sbase + g) ^ (ar & 7);
            *reinterpret_cast<u16x8*>(&Ahi[ar][slot * 8]) = hv;
            *reinterpret_cast<u16x8*>(&Alo[ar][slot * 8]) = lv;
        }
    }

    float twoinv[16];
    #pragma unroll
    for (int r = 0; r < 16; ++r)
        twoinv[r] = 2.0f * invn[r0 + wy * 32 + (r & 3) + 8 * (r >> 2) + 4 * l5];

    float m1[16], m2[16]; int i1[16];
    #pragma unroll
    for (int r = 0; r < 16; ++r) { m1[r] = INFINITY; m2[r] = INFINITY; i1[r] = 0; }

    const int cc = t >> 2;
    const int sbase = (t & 3) * 8;
    float4 pre[16];
    {
        const float* wb = w + (size_t)cc * DD + (t & 3) * 64;
        #pragma unroll
        for (int q = 0; q < 16; ++q) pre[q] = reinterpret_cast<const float4*>(wb)[q];
    }
    float wsq_pre = (t < 64) ? wsq[t] : 0.f;

    const int am = wy * 32 + lq;
    const int bn = wx * 32 + lq;
    const int sxor = lq & 7;

    for (int ch = 0; ch < 128; ++ch) {
        __syncthreads();
        #pragma unroll
        for (int g = 0; g < 8; ++g) {
            u16x8 hv, lv;
            split8(pre[2 * g], pre[2 * g + 1], hv, lv);
            int slot = (sbase + g) ^ (cc & 7);
            *reinterpret_cast<u16x8*>(&Bhi[cc][slot * 8]) = hv;
            *reinterpret_cast<u16x8*>(&Blo[cc][slot * 8]) = lv;
        }
        if (t < 64) wsq_s[t] = wsq_pre;
        __syncthreads();

        if (ch < 127) {
            const float* wb = w + (size_t)((ch + 1) * 64 + cc) * DD + (t & 3) * 64;
            #pragma unroll
            for (int q = 0; q < 16; ++q) pre[q] = reinterpret_cast<const float4*>(wb)[q];
            if (t < 64) wsq_pre = wsq[(ch + 1) * 64 + t];
        }

        f32x16 acc0, acc1;
        #pragma unroll
        for (int r = 0; r < 16; ++r) { acc0[r] = 0.f; acc1[r] = 0.f; }

        #pragma unroll
        for (int s = 0; s < 16; ++s) {
            const int sl = (2 * s + l5) ^ sxor;
            bf16x8 ah = *reinterpret_cast<const bf16x8*>(&Ahi[am][sl * 8]);
            bf16x8 al = *reinterpret_cast<const bf16x8*>(&Alo[am][sl * 8]);
            bf16x8 bh = *reinterpret_cast<const bf16x8*>(&Bhi[bn][sl * 8]);
            bf16x8 bl = *reinterpret_cast<const bf16x8*>(&Blo[bn][sl * 8]);
            acc0 = __builtin_amdgcn_mfma_f32_32x32x16_bf16(ah, bh, acc0, 0, 0, 0);
            acc1 = __builtin_amdgcn_mfma_f32_32x32x16_bf16(ah, bl, acc1, 0, 0, 0);
            acc0 = __builtin_amdgcn_mfma_f32_32x32x16_bf16(al, bh, acc0, 0, 0, 0);
        }

        const float wq = wsq_s[bn];
        const int nidx = ch * 64 + bn;
        #pragma unroll
        for (int r = 0; r < 16; ++r) {
            float v = wq - twoinv[r] * (acc0[r] + acc1[r]);
            if (v < m1[r]) { m2[r] = m1[r]; m1[r] = v; i1[r] = nidx; }
            else if (v < m2[r]) m2[r] = v;
        }
    }

    #pragma unroll
    for (int off = 1; off < 32; off <<= 1) {
        #pragma unroll
        for (int r = 0; r < 16; ++r) {
            float om1 = __shfl_xor(m1[r], off, 64);
            float om2 = __shfl_xor(m2[r], off, 64);
            int   oi  = __shfl_xor(i1[r], off, 64);
            if (om1 < m1[r] || (om1 == m1[r] && oi < i1[r])) {
                m2[r] = fminf(m1[r], om2); m1[r] = om1; i1[r] = oi;
            } else {
                m2[r] = fminf(om1, m2[r]);
            }
        }
    }
    if (lq == 0) {
        #pragma unroll
        for (int r = 0; r < 16; ++r) {
            int ml = wy * 32 + (r & 3) + 8 * (r >> 2) + 4 * l5;
            red_m1[wx][ml] = m1[r];
            red_m2[wx][ml] = m2[r];
            red_i1[wx][ml] = i1[r];
        }
    }
    __syncthreads();
    if (t < 64) {
        float a1 = red_m1[0][t], a2 = red_m2[0][t]; int ai = red_i1[0][t];
        float b1 = red_m1[1][t], b2 = red_m2[1][t]; int bi = red_i1[1][t];
        float f1, f2; int fi;
        if (b1 < a1 || (b1 == a1 && bi < ai)) { f1 = b1; fi = bi; f2 = fminf(a1, b2); }
        else                                  { f1 = a1; fi = ai; f2 = fminf(b1, a2); }
        idx_out[r0 + t] = fi;
        if (f2 - f1 < MARGIN) {
            int p = atomicAdd(counter, 1);
            list[p] = r0 + t;
        }
    }
}

extern "C" void kernel_launch(void* const* d_in, const int* in_sizes, int n_in,
                              void* d_out, int out_size, void* d_ws, size_t ws_size,
                              hipStream_t stream) {
    const float* z = (const float*)d_in[0];
    const float* w = (const float*)d_in[1];
    float* out = (float*)d_out;
    char* ws = (char*)d_ws;

    if (ws_size >= W2_NEED) {
        unsigned short* wtile = (unsigned short*)(ws + W2_WTILE);
        float* pm1 = (float*)(ws + W2_PM1);
        float* pm2 = (float*)(ws + W2_PM2);
        int*   pi1 = (int*)(ws + W2_PI1);
        int*   idx = (int*)(ws + W2_IDX);
        int*   cnt = (int*)(ws + W2_CNT);
        int*   list = (int*)(ws + W2_LIST);
        double* pbv = (double*)(ws + W2_PBV);
        int*    pbi = (int*)(ws + W2_PBI);
        u16x8* zt = (u16x8*)d_out;     // z_q region doubles as zt scratch

        hipMemsetAsync(cnt, 0, 4, stream);
        prep_kernel<<<640, 256, 0, stream>>>(z, w, zt, wtile);
        argmin2<<<256, 512, 0, stream>>>(zt, wtile, pm1, pm2, pi1);
        merge_kernel<<<64, 256, 0, stream>>>(pm1, pm2, pi1, idx, cnt, list);
        refine_kernel<<<2048, 256, 0, stream>>>(z, w, cnt, list, idx, pbv, pbi);
        refine2_kernel<<<64, 256, 0, stream>>>(cnt, list, pbv, pbi, idx);
        gather_kernel<<<BT / 8, 256, 0, stream>>>(w, idx, out);
    } else {
        float* inv  = (float*)(ws + WS_INV);
        float* wsq  = (float*)(ws + WS_WSQ);
        int*   idx  = (int*)(ws + WS_IDX);
        int*   cnt  = (int*)(ws + WS_CNT);
        int*   list = (int*)(ws + WS_LIST);

        hipMemsetAsync(cnt, 0, 4, stream);
        rownorm_kernel<<<BT / 4, 256, 0, stream>>>(z, BT, inv, 0);
        rownorm_kernel<<<NB / 4, 256, 0, stream>>>(w, NB, wsq, 1);
        argmin_mfma<<<BT / 64, 256, 0, stream>>>(z, w, inv, wsq, idx, cnt, list);
        refine_full_kernel<<<64, 256, 0, stream>>>(z, w, cnt, list, idx);
        gather_kernel<<<BT / 8, 256, 0, stream>>>(w, idx, out);
    }
}

// Round 21
// 326.506 us; speedup vs baseline: 3.6783x; 1.0007x over previous
//
#include <hip/hip_runtime.h>
#include <hip/hip_bf16.h>

#define BT 16384
#define NB 8192
#define DD 256
#define MARGIN 2e-4f
#define MAXITEM 4096

typedef short bf16x8 __attribute__((ext_vector_type(8)));
typedef unsigned short u16x8 __attribute__((ext_vector_type(8)));
typedef float f32x4 __attribute__((ext_vector_type(4)));
typedef __attribute__((address_space(1))) unsigned int gu32;
typedef __attribute__((address_space(3))) unsigned int lu32;

// ---- fast-path ws layout (bytes) ----
#define W2_WTILE 0
#define W2_PM1   (8*1024*1024)
#define W2_PM2   (W2_PM1 + 2*BT*4)
#define W2_PI1   (W2_PM2 + 2*BT*4)
#define W2_IDX   (W2_PI1 + 2*BT*4)
#define W2_CNT   (W2_IDX + BT*4)
#define W2_LIST  (W2_CNT + 256)
#define W2_PBV   (W2_LIST + BT*4)
#define W2_PBI   (W2_PBV + MAXITEM*16*8)
#define W2_NEED  ((size_t)(W2_PBI + MAXITEM*16*4))

// ---- fallback ws layout (round-4, validated) ----
#define WS_INV  0
#define WS_WSQ  (BT*4)
#define WS_IDX  (WS_WSQ + NB*4)
#define WS_CNT  (WS_IDX + BT*4)
#define WS_LIST (WS_CNT + 64)

__device__ __forceinline__ unsigned int f2bf(float f) {
    unsigned int u = __float_as_uint(f);
    return (u + 0x7FFFu + ((u >> 16) & 1u)) >> 16;
}

__device__ __forceinline__ void split8(const float4 a, const float4 b, u16x8 &hv, u16x8 &lv) {
    float xs[8] = {a.x, a.y, a.z, a.w, b.x, b.y, b.z, b.w};
    #pragma unroll
    for (int i = 0; i < 8; ++i) {
        unsigned int h = f2bf(xs[i]);
        hv[i] = (unsigned short)h;
        lv[i] = (unsigned short)f2bf(xs[i] - __uint_as_float(h << 16));
    }
}

// ================= FAST PATH =================

// Fused prep: blocks 0..511 = zsplit (normalize+split z), 512..639 = wsplit.
__global__ void prep_kernel(const float* __restrict__ z,
                            const float* __restrict__ w,
                            u16x8* __restrict__ zt,
                            unsigned short* __restrict__ wtile) {
    const int t = threadIdx.x;
    if (blockIdx.x >= 512) {
        const int ch = blockIdx.x - 512;
        const int c  = t >> 2;
        const int q  = t & 3;
        const float* wr = w + (size_t)(ch * 64 + c) * DD + q * 64;
        unsigned short* base = wtile + (size_t)ch * 32768;
        #pragma unroll
        for (int g = 0; g < 8; ++g) {
            float4 v0 = reinterpret_cast<const float4*>(wr)[2 * g];
            float4 v1 = reinterpret_cast<const float4*>(wr)[2 * g + 1];
            u16x8 hv, lv;
            split8(v0, v1, hv, lv);
            const int slot = q * 8 + g;
            *reinterpret_cast<u16x8*>(base + ((size_t)slot * 64 + c) * 8) = hv;
            *reinterpret_cast<u16x8*>(base + ((size_t)(32 + slot) * 64 + c) * 8) = lv;
        }
        return;
    }
    __shared__ float inv_s[32];
    const int rt = blockIdx.x;
    {
        const int rl = t >> 3, sub = t & 7;
        const float4* zr = reinterpret_cast<const float4*>(
            z + (size_t)(rt * 32 + rl) * DD + sub * 32);
        double s = 0.0;
        #pragma unroll
        for (int i = 0; i < 8; ++i) {
            float4 v = zr[i];
            s += (double)v.x*v.x + (double)v.y*v.y + (double)v.z*v.z + (double)v.w*v.w;
        }
        s += __shfl_xor(s, 1, 64);
        s += __shfl_xor(s, 2, 64);
        s += __shfl_xor(s, 4, 64);
        if (sub == 0) {
            double n = sqrt(s);
            if (n < 1e-12) n = 1e-12;
            inv_s[rl] = (float)(1.0 / n);
        }
    }
    __syncthreads();
    const int sg = t >> 6, l = t & 63;
    const int tau  = rt * 2 + (sg >> 1);
    const int rowl = (sg >> 1) * 16 + (l & 15);
    const int row  = rt * 32 + rowl;
    const float inv = inv_s[rowl];
    #pragma unroll
    for (int ksi = 0; ksi < 4; ++ksi) {
        const int ks = (sg & 1) * 4 + ksi;
        const int k0 = ks * 32 + (l >> 4) * 8;
        float4 a = *reinterpret_cast<const float4*>(z + (size_t)row * DD + k0);
        float4 b = *reinterpret_cast<const float4*>(z + (size_t)row * DD + k0 + 4);
        a.x *= inv; a.y *= inv; a.z *= inv; a.w *= inv;
        b.x *= inv; b.y *= inv; b.z *= inv; b.w *= inv;
        u16x8 hv, lv;
        split8(a, b, hv, lv);
        const size_t o = ((size_t)tau * 8 + ks) * 64 + l;
        zt[o] = hv;
        zt[524288 + o] = lv;
    }
}

// Fused MFMA argmin, 16x16x32 (round-20 validated: 257us, no spill).
// Round-21 change: A-fragments pinned to arch VGPRs (demand 88+64=152<256)
// to eliminate suspected v_accvgpr_read operand traffic (VALUBusy 42%).
__launch_bounds__(512, 1)
__global__ void argmin2(const u16x8* __restrict__ zt,
                        const unsigned short* __restrict__ wtile,
                        float* __restrict__ pm1,
                        float* __restrict__ pm2,
                        int* __restrict__ pi1) {
    __shared__ __align__(16) unsigned short Bbuf[2][2][32][64][8]; // 128 KB
    const int t = threadIdx.x, lane = t & 63, wv = t >> 6;
    const int b = blockIdx.x;
    const int rb   = b >> 1;
    const int half = b & 1;
    const int r0   = rb * 128;
    const int tau  = rb * 8 + wv;
    const int lc = lane & 15;
    const int lk = lane >> 4;

    const bf16x8* zf = reinterpret_cast<const bf16x8*>(zt);
    bf16x8 ah[8], al[8];
    #pragma unroll
    for (int ks = 0; ks < 8; ++ks) {
        const size_t o = ((size_t)tau * 8 + ks) * 64 + lane;
        ah[ks] = zf[o];
        al[ks] = zf[524288 + o];
    }
    #pragma unroll
    for (int ks = 0; ks < 8; ++ks) {
        asm volatile("" : "+v"(ah[ks]));
        asm volatile("" : "+v"(al[ks]));
    }

    float m1[4], m2[4]; int i1[4];
    #pragma unroll
    for (int j = 0; j < 4; ++j) { m1[j] = INFINITY; m2[j] = INFINITY; i1[j] = 0; }

    const unsigned short* wsrc = wtile + (size_t)half * 2097152 + (size_t)t * 8;
    unsigned short* dst0 = &Bbuf[0][0][0][0][0] + (size_t)t * 8;
    unsigned short* dst1 = &Bbuf[1][0][0][0][0] + (size_t)t * 8;

    {
        #pragma unroll
        for (int i = 0; i < 8; ++i)
            __builtin_amdgcn_global_load_lds((gu32*)(wsrc + i * 4096),
                                             (lu32*)(dst0 + i * 4096), 16, 0, 0);
    }

    int cur = 0;
    for (int ch = 0; ch < 64; ++ch) {
        if (ch < 63) {
            const unsigned short* src = wsrc + (size_t)(ch + 1) * 32768;
            unsigned short* dst = cur ? dst0 : dst1;
            #pragma unroll
            for (int i = 0; i < 8; ++i)
                __builtin_amdgcn_global_load_lds((gu32*)(src + i * 4096),
                                                 (lu32*)(dst + i * 4096), 16, 0, 0);
            asm volatile("s_waitcnt vmcnt(8)" ::: "memory");
        } else {
            asm volatile("s_waitcnt vmcnt(0)" ::: "memory");
        }
        __builtin_amdgcn_s_barrier();
        __builtin_amdgcn_sched_barrier(0);

        f32x4 a0 = {0.f,0.f,0.f,0.f}, a1 = a0, a2 = a0, a3 = a0;

        #pragma unroll
        for (int ks = 0; ks < 8; ++ks) {
            const int slot = ks * 4 + lk;
            const bf16x8* Bh = reinterpret_cast<const bf16x8*>(&Bbuf[cur][0][slot][0][0]);
            const bf16x8* Bl = reinterpret_cast<const bf16x8*>(&Bbuf[cur][1][slot][0][0]);
            bf16x8 bh, bl;
            bh = Bh[lc];      bl = Bl[lc];
            a0 = __builtin_amdgcn_mfma_f32_16x16x32_bf16(ah[ks], bh, a0, 0, 0, 0);
            a0 = __builtin_amdgcn_mfma_f32_16x16x32_bf16(ah[ks], bl, a0, 0, 0, 0);
            a0 = __builtin_amdgcn_mfma_f32_16x16x32_bf16(al[ks], bh, a0, 0, 0, 0);
            bh = Bh[16 + lc]; bl = Bl[16 + lc];
            a1 = __builtin_amdgcn_mfma_f32_16x16x32_bf16(ah[ks], bh, a1, 0, 0, 0);
            a1 = __builtin_amdgcn_mfma_f32_16x16x32_bf16(ah[ks], bl, a1, 0, 0, 0);
            a1 = __builtin_amdgcn_mfma_f32_16x16x32_bf16(al[ks], bh, a1, 0, 0, 0);
            bh = Bh[32 + lc]; bl = Bl[32 + lc];
            a2 = __builtin_amdgcn_mfma_f32_16x16x32_bf16(ah[ks], bh, a2, 0, 0, 0);
            a2 = __builtin_amdgcn_mfma_f32_16x16x32_bf16(ah[ks], bl, a2, 0, 0, 0);
            a2 = __builtin_amdgcn_mfma_f32_16x16x32_bf16(al[ks], bh, a2, 0, 0, 0);
            bh = Bh[48 + lc]; bl = Bl[48 + lc];
            a3 = __builtin_amdgcn_mfma_f32_16x16x32_bf16(ah[ks], bh, a3, 0, 0, 0);
            a3 = __builtin_amdgcn_mfma_f32_16x16x32_bf16(ah[ks], bl, a3, 0, 0, 0);
            a3 = __builtin_amdgcn_mfma_f32_16x16x32_bf16(al[ks], bh, a3, 0, 0, 0);
        }

        const int nb = half * 4096 + ch * 64 + lc;
        #pragma unroll
        for (int j = 0; j < 4; ++j) {
            float v;
            v = -2.0f * a0[j];
            if (v < m1[j]) { m2[j] = m1[j]; m1[j] = v; i1[j] = nb; }
            else if (v < m2[j]) m2[j] = v;
            v = -2.0f * a1[j];
            if (v < m1[j]) { m2[j] = m1[j]; m1[j] = v; i1[j] = nb + 16; }
            else if (v < m2[j]) m2[j] = v;
            v = -2.0f * a2[j];
            if (v < m1[j]) { m2[j] = m1[j]; m1[j] = v; i1[j] = nb + 32; }
            else if (v < m2[j]) m2[j] = v;
            v = -2.0f * a3[j];
            if (v < m1[j]) { m2[j] = m1[j]; m1[j] = v; i1[j] = nb + 48; }
            else if (v < m2[j]) m2[j] = v;
        }

        __builtin_amdgcn_sched_barrier(0);
        __builtin_amdgcn_s_barrier();
        cur ^= 1;
    }

    #pragma unroll
    for (int off = 1; off < 16; off <<= 1) {
        #pragma unroll
        for (int j = 0; j < 4; ++j) {
            float om1 = __shfl_xor(m1[j], off, 64);
            float om2 = __shfl_xor(m2[j], off, 64);
            int   oi  = __shfl_xor(i1[j], off, 64);
            if (om1 < m1[j] || (om1 == m1[j] && oi < i1[j])) {
                m2[j] = fminf(m1[j], om2); m1[j] = om1; i1[j] = oi;
            } else {
                m2[j] = fminf(om1, m2[j]);
            }
        }
    }
    if (lc == 0) {
        #pragma unroll
        for (int j = 0; j < 4; ++j) {
            const int row = r0 + wv * 16 + lk * 4 + j;
            pm1[half * BT + row] = m1[j];
            pm2[half * BT + row] = m2[j];
            pi1[half * BT + row] = i1[j];
        }
    }
}

// merge the two code-halves per row; flag near-ties for refine
__global__ void merge_kernel(const float* __restrict__ pm1,
                             const float* __restrict__ pm2,
                             const int* __restrict__ pi1,
                             int* __restrict__ idx_out,
                             int* __restrict__ counter,
                             int* __restrict__ list) {
    const int r = blockIdx.x * 256 + threadIdx.x;
    float a1 = pm1[r], a2 = pm2[r]; int ai = pi1[r];
    float b1 = pm1[BT + r], b2 = pm2[BT + r]; int bi = pi1[BT + r];
    float f1, f2; int fi;
    if (b1 < a1 || (b1 == a1 && bi < ai)) { f1 = b1; fi = bi; f2 = fminf(a1, b2); }
    else                                  { f1 = a1; fi = ai; f2 = fminf(b1, a2); }
    idx_out[r] = fi;
    if (f2 - f1 < MARGIN) {
        int p = atomicAdd(counter, 1);
        list[p] = r;
    }
}

// ================= SHARED (refine / gather) =================

// refine v5 (round-20 validated): item x 16-segment decomposition.
__global__ void refine_kernel(const float* __restrict__ z,
                              const float* __restrict__ w,
                              const int* __restrict__ counter,
                              const int* __restrict__ list,
                              int* __restrict__ idx_out,
                              double* __restrict__ pbv,
                              int* __restrict__ pbi) {
    __shared__ double zn_s[256];
    __shared__ float  znf[256];
    __shared__ float  dist[512];
    __shared__ double rv[256];
    __shared__ int    ri[256];
    __shared__ float  fm[256];
    const int t = threadIdx.x;
    const int lane = t & 63;
    const int wv = t >> 6;
    const int cnt = *counter;
    const int nit = (cnt < MAXITEM) ? cnt : MAXITEM;
    const long long npair = (long long)nit * 16;

    for (long long p = blockIdx.x; p < npair; p += gridDim.x) {
        const int item = (int)(p >> 4), seg = (int)(p & 15);
        const int row = list[item];
        double zv = (double)z[(size_t)row * DD + t];
        __syncthreads();
        rv[t] = zv * zv;
        __syncthreads();
        for (int s = 128; s; s >>= 1) { if (t < s) rv[t] += rv[t + s]; __syncthreads(); }
        double norm = sqrt(rv[0]);
        if (norm < 1e-12) norm = 1e-12;
        __syncthreads();
        zn_s[t] = zv / norm;
        znf[t] = (float)(zv / norm);
        __syncthreads();

        const float4 zn4 = *reinterpret_cast<const float4*>(&znf[lane * 4]);
        const int nbase = seg * 512;

        for (int o = wv * 4; o < 512; o += 16) {
            float d[4];
            #pragma unroll
            for (int i = 0; i < 4; ++i) {
                float4 v = *reinterpret_cast<const float4*>(
                    w + (size_t)(nbase + o + i) * DD + lane * 4);
                d[i] = (v.x * v.x + v.y * v.y + v.z * v.z + v.w * v.w)
                     - 2.f * (v.x * zn4.x + v.y * zn4.y + v.z * zn4.z + v.w * zn4.w);
            }
            #pragma unroll
            for (int off = 32; off; off >>= 1) {
                #pragma unroll
                for (int i = 0; i < 4; ++i) d[i] += __shfl_down(d[i], off, 64);
            }
            if (lane == 0) {
                dist[o] = d[0]; dist[o + 1] = d[1];
                dist[o + 2] = d[2]; dist[o + 3] = d[3];
            }
        }
        __syncthreads();

        fm[t] = fminf(dist[t], dist[t + 256]);
        __syncthreads();
        for (int s = 128; s; s >>= 1) { if (t < s) fm[t] = fminf(fm[t], fm[t + s]); __syncthreads(); }
        const float thresh = fm[0] + 1e-3f;

        double bv = INFINITY; int bi = 0x7fffffff;
        #pragma unroll
        for (int j = 0; j < 2; ++j) {
            const int nl = t + j * 256;
            if (dist[nl] <= thresh) {
                const int n = nbase + nl;
                const float* wr = w + (size_t)n * DD;
                double dot = 0.0, wsqd = 0.0;
                for (int k = 0; k < DD; ++k) {
                    double wvv = (double)wr[k];
                    dot  += zn_s[k] * wvv;
                    wsqd += wvv * wvv;
                }
                double d2 = wsqd - 2.0 * dot;
                if (d2 < bv || (d2 == bv && n < bi)) { bv = d2; bi = n; }
            }
        }
        __syncthreads();
        rv[t] = bv; ri[t] = bi;
        __syncthreads();
        for (int s = 128; s; s >>= 1) {
            if (t < s) {
                if (rv[t + s] < rv[t] || (rv[t + s] == rv[t] && ri[t + s] < ri[t])) {
                    rv[t] = rv[t + s]; ri[t] = ri[t + s];
                }
            }
            __syncthreads();
        }
        if (t == 0) { pbv[p] = rv[0]; pbi[p] = ri[0]; }
        __syncthreads();
    }

    for (int item = MAXITEM + blockIdx.x; item < cnt; item += gridDim.x) {
        const int row = list[item];
        double zv = (double)z[(size_t)row * DD + t];
        __syncthreads();
        rv[t] = zv * zv;
        __syncthreads();
        for (int s = 128; s; s >>= 1) { if (t < s) rv[t] += rv[t + s]; __syncthreads(); }
        double norm = sqrt(rv[0]);
        if (norm < 1e-12) norm = 1e-12;
        __syncthreads();
        zn_s[t] = zv / norm;
        __syncthreads();
        double bv = INFINITY; int bi = 0x7fffffff;
        for (int n = t; n < NB; n += 256) {
            const float* wr = w + (size_t)n * DD;
            double dot = 0.0, wsqd = 0.0;
            for (int k = 0; k < DD; ++k) {
                double wvv = (double)wr[k];
                dot  += zn_s[k] * wvv;
                wsqd += wvv * wvv;
            }
            double d2 = wsqd - 2.0 * dot;
            if (d2 < bv || (d2 == bv && n < bi)) { bv = d2; bi = n; }
        }
        __syncthreads();
        rv[t] = bv; ri[t] = bi;
        __syncthreads();
        for (int s = 128; s; s >>= 1) {
            if (t < s) {
                if (rv[t + s] < rv[t] || (rv[t + s] == rv[t] && ri[t + s] < ri[t])) {
                    rv[t] = rv[t + s]; ri[t] = ri[t + s];
                }
            }
            __syncthreads();
        }
        if (t == 0) idx_out[row] = ri[0];
        __syncthreads();
    }
}

// merge the 16 per-segment partials of each item (same arbiter)
__global__ void refine2_kernel(const int* __restrict__ counter,
                               const int* __restrict__ list,
                               const double* __restrict__ pbv,
                               const int* __restrict__ pbi,
                               int* __restrict__ idx_out) {
    const int item = blockIdx.x * 256 + threadIdx.x;
    const int cnt = *counter;
    const int nit = (cnt < MAXITEM) ? cnt : MAXITEM;
    if (item >= nit) return;
    double bv = INFINITY; int bi = 0x7fffffff;
    #pragma unroll 4
    for (int s = 0; s < 16; ++s) {
        double v = pbv[(long long)item * 16 + s];
        int    i = pbi[(long long)item * 16 + s];
        if (v < bv || (v == bv && i < bi)) { bv = v; bi = i; }
    }
    idx_out[list[item]] = bi;
}

__global__ void gather_kernel(const float* __restrict__ w,
                              const int* __restrict__ idx,
                              float* __restrict__ out) {
    const int t = threadIdx.x;
    const int blk = blockIdx.x;
    const int row = blk * 8 + (t >> 5);
    const int lane = t & 31;
    int n = idx[row];
    if ((unsigned)n >= (unsigned)NB) n = 0;
    const float4* src = reinterpret_cast<const float4*>(w + (size_t)n * DD + lane * 8);
    float4 v0 = src[0], v1 = src[1];
    float4* dst = reinterpret_cast<float4*>(out + (size_t)row * DD + lane * 8);
    dst[0] = v0;
    dst[1] = v1;
    if (t < 8) {
        int r2 = blk * 8 + t;
        out[(size_t)BT * DD + r2] = (float)idx[r2];
    }
}

// ================= FALLBACK (round-4, validated) =================

__global__ void rownorm_kernel(const float* __restrict__ x, int rows,
                               float* __restrict__ out, int mode) {
    int row  = blockIdx.x * 4 + (threadIdx.x >> 6);
    int lane = threadIdx.x & 63;
    if (row >= rows) return;
    const float4 v = *reinterpret_cast<const float4*>(x + (size_t)row * DD + lane * 4);
    double s = (double)v.x * v.x + (double)v.y * v.y + (double)v.z * v.z + (double)v.w * v.w;
    #pragma unroll
    for (int off = 32; off; off >>= 1) s += __shfl_down(s, off, 64);
    if (lane == 0) {
        if (mode == 0) {
            double n = sqrt(s);
            if (n < 1e-12) n = 1e-12;
            out[row] = (float)(1.0 / n);
        } else {
            out[row] = (float)s;
        }
    }
}

__global__ void refine_full_kernel(const float* __restrict__ z,
                                   const float* __restrict__ w,
                                   const int* __restrict__ counter,
                                   const int* __restrict__ list,
                                   int* __restrict__ idx_out) {
    __shared__ double zn_s[256];
    __shared__ double rv[256];
    __shared__ int    ri[256];
    const int t = threadIdx.x;
    const int cnt = *counter;
    for (int item = blockIdx.x; item < cnt; item += gridDim.x) {
        const int row = list[item];
        double zv = (double)z[(size_t)row * DD + t];
        __syncthreads();
        rv[t] = zv * zv;
        __syncthreads();
        for (int s = 128; s; s >>= 1) { if (t < s) rv[t] += rv[t + s]; __syncthreads(); }
        double norm = sqrt(rv[0]);
        if (norm < 1e-12) norm = 1e-12;
        __syncthreads();
        zn_s[t] = zv / norm;
        __syncthreads();
        double bv = INFINITY; int bi = 0;
        for (int n = t; n < NB; n += 256) {
            double dot = 0.0, wsqd = 0.0;
            const float* wr = w + (size_t)n * DD;
            for (int k = 0; k < DD; ++k) {
                double wv = (double)wr[k];
                dot  += zn_s[k] * wv;
                wsqd += wv * wv;
            }
            double dist = wsqd - 2.0 * dot;
            if (dist < bv) { bv = dist; bi = n; }
        }
        __syncthreads();
        rv[t] = bv; ri[t] = bi;
        __syncthreads();
        for (int s = 128; s; s >>= 1) {
            if (t < s) {
                if (rv[t + s] < rv[t] || (rv[t + s] == rv[t] && ri[t + s] < ri[t])) {
                    rv[t] = rv[t + s]; ri[t] = ri[t + s];
                }
            }
            __syncthreads();
        }
        if (t == 0) idx_out[row] = ri[0];
        __syncthreads();
    }
}

__launch_bounds__(256, 1)
__global__ void argmin_mfma(const float* __restrict__ z,
                            const float* __restrict__ w,
                            const float* __restrict__ invn,
                            const float* __restrict__ wsq,
                            int* __restrict__ idx_out,
                            int* __restrict__ counter,
                            int* __restrict__ list) {
    __shared__ unsigned short Ahi[64][256];
    __shared__ unsigned short Alo[64][256];
    __shared__ unsigned short Bhi[64][256];
    __shared__ unsigned short Blo[64][256];
    __shared__ float wsq_s[64];
    __shared__ float red_m1[2][64];
    __shared__ float red_m2[2][64];
    __shared__ int   red_i1[2][64];

    typedef float f32x16 __attribute__((ext_vector_type(16)));
    const int t    = threadIdx.x;
    const int lane = t & 63;
    const int wvv  = t >> 6;
    const int wy = wvv >> 1, wx = wvv & 1;
    const int l5 = lane >> 5, lq = lane & 31;
    const int r0 = blockIdx.x * 64;

    {
        const int ar = t >> 2;
        const int sbase = (t & 3) * 8;
        const float* zr = z + (size_t)(r0 + ar) * DD + (t & 3) * 64;
        #pragma unroll
        for (int g = 0; g < 8; ++g) {
            float4 v0 = reinterpret_cast<const float4*>(zr)[2 * g];
            float4 v1 = reinterpret_cast<const float4*>(zr)[2 * g + 1];
            u16x8 hv, lv;
            split8(v0, v1, hv, lv);
            int slot = (sbase + g) ^ (ar & 7);
            *reinterpret_cast<u16x8*>(&Ahi[ar][slot * 8]) = hv;
            *reinterpret_cast<u16x8*>(&Alo[ar][slot * 8]) = lv;
        }
    }

    float twoinv[16];
    #pragma unroll
    for (int r = 0; r < 16; ++r)
        twoinv[r] = 2.0f * invn[r0 + wy * 32 + (r & 3) + 8 * (r >> 2) + 4 * l5];

    float m1[16], m2[16]; int i1[16];
    #pragma unroll
    for (int r = 0; r < 16; ++r) { m1[r] = INFINITY; m2[r] = INFINITY; i1[r] = 0; }

    const int cc = t >> 2;
    const int sbase = (t & 3) * 8;
    float4 pre[16];
    {
        const float* wb = w + (size_t)cc * DD + (t & 3) * 64;
        #pragma unroll
        for (int q = 0; q < 16; ++q) pre[q] = reinterpret_cast<const float4*>(wb)[q];
    }
    float wsq_pre = (t < 64) ? wsq[t] : 0.f;

    const int am = wy * 32 + lq;
    const int bn = wx * 32 + lq;
    const int sxor = lq & 7;

    for (int ch = 0; ch < 128; ++ch) {
        __syncthreads();
        #pragma unroll
        for (int g = 0; g < 8; ++g) {
            u16x8 hv, lv;
            split8(pre[2 * g], pre[2 * g + 1], hv, lv);
            int slot = (sbase + g) ^ (cc & 7);
            *reinterpret_cast<u16x8*>(&Bhi[cc][slot * 8]) = hv;
            *reinterpret_cast<u16x8*>(&Blo[cc][slot * 8]) = lv;
        }
        if (t < 64) wsq_s[t] = wsq_pre;
        __syncthreads();

        if (ch < 127) {
            const float* wb = w + (size_t)((ch + 1) * 64 + cc) * DD + (t & 3) * 64;
            #pragma unroll
            for (int q = 0; q < 16; ++q) pre[q] = reinterpret_cast<const float4*>(wb)[q];
            if (t < 64) wsq_pre = wsq[(ch + 1) * 64 + t];
        }

        f32x16 acc0, acc1;
        #pragma unroll
        for (int r = 0; r < 16; ++r) { acc0[r] = 0.f; acc1[r] = 0.f; }

        #pragma unroll
        for (int s = 0; s < 16; ++s) {
            const int sl = (2 * s + l5) ^ sxor;
            bf16x8 ah = *reinterpret_cast<const bf16x8*>(&Ahi[am][sl * 8]);
            bf16x8 al = *reinterpret_cast<const bf16x8*>(&Alo[am][sl * 8]);
            bf16x8 bh = *reinterpret_cast<const bf16x8*>(&Bhi[bn][sl * 8]);
            bf16x8 bl = *reinterpret_cast<const bf16x8*>(&Blo[bn][sl * 8]);
            acc0 = __builtin_amdgcn_mfma_f32_32x32x16_bf16(ah, bh, acc0, 0, 0, 0);
            acc1 = __builtin_amdgcn_mfma_f32_32x32x16_bf16(ah, bl, acc1, 0, 0, 0);
            acc0 = __builtin_amdgcn_mfma_f32_32x32x16_bf16(al, bh, acc0, 0, 0, 0);
        }

        const float wq = wsq_s[bn];
        const int nidx = ch * 64 + bn;
        #pragma unroll
        for (int r = 0; r < 16; ++r) {
            float v = wq - twoinv[r] * (acc0[r] + acc1[r]);
            if (v < m1[r]) { m2[r] = m1[r]; m1[r] = v; i1[r] = nidx; }
            else if (v < m2[r]) m2[r] = v;
        }
    }

    #pragma unroll
    for (int off = 1; off < 32; off <<= 1) {
        #pragma unroll
        for (int r = 0; r < 16; ++r) {
            float om1 = __shfl_xor(m1[r], off, 64);
            float om2 = __shfl_xor(m2[r], off, 64);
            int   oi  = __shfl_xor(i1[r], off, 64);
            if (om1 < m1[r] || (om1 == m1[r] && oi < i1[r])) {
                m2[r] = fminf(m1[r], om2); m1[r] = om1; i1[r] = oi;
            } else {
                m2[r] = fminf(om1, m2[r]);
            }
        }
    }
    if (lq == 0) {
        #pragma unroll
        for (int r = 0; r < 16; ++r) {
            int ml = wy * 32 + (r & 3) + 8 * (r >> 2) + 4 * l5;
            red_m1[wx][ml] = m1[r];
            red_m2[wx][ml] = m2[r];
            red_i1[wx][ml] = i1[r];
        }
    }
    __syncthreads();
    if (t < 64) {
        float a1 = red_m1[0][t], a2 = red_m2[0][t]; int ai = red_i1[0][t];
        float b1 = red_m1[1][t], b2 = red_m2[1][t]; int bi = red_i1[1][t];
        float f1, f2; int fi;
        if (b1 < a1 || (b1 == a1 && bi < ai)) { f1 = b1; fi = bi; f2 = fminf(a1, b2); }
        else                                  { f1 = a1; fi = ai; f2 = fminf(b1, a2); }
        idx_out[r0 + t] = fi;
        if (f2 - f1 < MARGIN) {
            int p = atomicAdd(counter, 1);
            list[p] = r0 + t;
        }
    }
}

extern "C" void kernel_launch(void* const* d_in, const int* in_sizes, int n_in,
                              void* d_out, int out_size, void* d_ws, size_t ws_size,
                              hipStream_t stream) {
    const float* z = (const float*)d_in[0];
    const float* w = (const float*)d_in[1];
    float* out = (float*)d_out;
    char* ws = (char*)d_ws;

    if (ws_size >= W2_NEED) {
        unsigned short* wtile = (unsigned short*)(ws + W2_WTILE);
        float* pm1 = (float*)(ws + W2_PM1);
        float* pm2 = (float*)(ws + W2_PM2);
        int*   pi1 = (int*)(ws + W2_PI1);
        int*   idx = (int*)(ws + W2_IDX);
        int*   cnt = (int*)(ws + W2_CNT);
        int*   list = (int*)(ws + W2_LIST);
        double* pbv = (double*)(ws + W2_PBV);
        int*    pbi = (int*)(ws + W2_PBI);
        u16x8* zt = (u16x8*)d_out;     // z_q region doubles as zt scratch

        hipMemsetAsync(cnt, 0, 4, stream);
        prep_kernel<<<640, 256, 0, stream>>>(z, w, zt, wtile);
        argmin2<<<256, 512, 0, stream>>>(zt, wtile, pm1, pm2, pi1);
        merge_kernel<<<64, 256, 0, stream>>>(pm1, pm2, pi1, idx, cnt, list);
        refine_kernel<<<2048, 256, 0, stream>>>(z, w, cnt, list, idx, pbv, pbi);
        refine2_kernel<<<64, 256, 0, stream>>>(cnt, list, pbv, pbi, idx);
        gather_kernel<<<BT / 8, 256, 0, stream>>>(w, idx, out);
    } else {
        float* inv  = (float*)(ws + WS_INV);
        float* wsq  = (float*)(ws + WS_WSQ);
        int*   idx  = (int*)(ws + WS_IDX);
        int*   cnt  = (int*)(ws + WS_CNT);
        int*   list = (int*)(ws + WS_LIST);

        hipMemsetAsync(cnt, 0, 4, stream);
        rownorm_kernel<<<BT / 4, 256, 0, stream>>>(z, BT, inv, 0);
        rownorm_kernel<<<NB / 4, 256, 0, stream>>>(w, NB, wsq, 1);
        argmin_mfma<<<BT / 64, 256, 0, stream>>>(z, w, inv, wsq, idx, cnt, list);
        refine_full_kernel<<<64, 256, 0, stream>>>(z, w, cnt, list, idx);
        gather_kernel<<<BT / 8, 256, 0, stream>>>(w, idx, out);
    }
}